// Round 10
// baseline (551.471 us; speedup 1.0000x reference)
//
#include <hip/hip_runtime.h>
#include <hip/hip_cooperative_groups.h>

namespace cg = cooperative_groups;

#define DEVFN __device__ __forceinline__

// NaN-propagating relu (fmaxf(NaN,0)==0 would mask upstream failures).
DEVFN float relu(float x) { return x < 0.f ? 0.f : x; }

// f16 pair helpers: weights/activations packed as half2 in k-major pairs.
typedef _Float16 h2 __attribute__((ext_vector_type(2)));
DEVFN float dot2(unsigned a, unsigned b, float c) {
    return __builtin_amdgcn_fdot2(__builtin_bit_cast(h2, a),
                                  __builtin_bit_cast(h2, b), c, false);
}
DEVFN unsigned pack2(float x, float y) {
    h2 h; h.x = (_Float16)x; h.y = (_Float16)y;
    return __builtin_bit_cast(unsigned, h);
}

// Packed-weight layout (round-8 interleaved tile [kp4][c][kp_in], proven):
//   d[kp4*(C*4) + c*4 + (kp&3)] = half2(W[2kp][c], W[2kp+1][c])
#define OFF_Q   0
#define OFF_K   8192
#define OFF_V   16384
#define OFF_O   24576
#define OFF_L1  32768
#define OFF_L2  49152
#define OFF_IN  65536
#define OFF_PE  69632
#define OFF_FU  73728

struct MegaParams {
    const float* features; const int* coords;
    const float* pe_w1; const float* pe_b1; const float* pe_w2; const float* pe_b2;
    const float* in_w;  const float* in_b;
    const float* q_w;   const float* q_b;
    const float* k_w;   const float* k_b;
    const float* v_w;   const float* v_b;
    const float* o_w;   const float* o_b;
    const float* n1_g;  const float* n1_b;
    const float* l1_w;  const float* l1_b;
    const float* l2_w;  const float* l2_b;
    const float* n3_g;  const float* n3_b;
    const float* fu_w;  const float* fu_b;
    const float* bn_g;  const float* bn_b;
    float* qs; float* ks; float* vs; int* nbr;
    float* bnSum; float* bnSq; unsigned* wH;
    float* out; int N;
};

// ---------------------------------------------------------------------------
// MEGA: pack -> (src proj + qkv, nbr top-16) -> attention+FFN+fusion -> BN.
// One cooperative launch, 512 blocks x 256 thr (2 tiles per block per phase),
// 3 grid syncs. Round-9 lesson: 1024 blocks = exactly max co-residency ->
// launch rejected, output stayed zero. 512 blocks with launch_bounds(256,2)
// leaves 3x capacity margin (LDS limit is 6/CU at 24.5KB). All compute
// bodies verbatim round-8 (dot2, tile-packed weights, bias folds; absmax
// 0.0156). Host checks the coop-launch return code and falls back to the
// proven 4-kernel pipeline on ANY error.
// ---------------------------------------------------------------------------
__global__ __launch_bounds__(256, 2) void mega_cst(MegaParams P)
{
    cg::grid_group grid = cg::this_grid();
    const int tid = threadIdx.x;
    const int bx = blockIdx.x;            // 0..511
    const int gid = bx * 256 + tid;

    __shared__ union SU {
        struct {                          // phase-1 (src + nbr; disjoint)
            float S[1024];
            unsigned SH[512];
            unsigned FHp[256];
            unsigned HHp[256];
            int sC[24];
            int cnt[8];
            int lst[8 * 64];
            int outL[128];
        } ka;
        struct {                          // phase-2 (attention/FFN/fusion)
            float A[1024]; float C[1024]; float Q[1024]; float SC[512];
            unsigned BtH[512]; unsigned CH[512]; unsigned FH[256];
            _Float16 Hh[2048]; float bK[128]; float bV[128]; int idxL[128];
        } k4;
    } U;

    // ================= phase 0: weight packing + BN zero ===================
    {
        const int stride = gridDim.x * 256;
        auto packmat = [&](const float* s, int K, int C, unsigned* d) {
            const int kp2 = K / 2;
            const int n = kp2 * C;
            const int c4 = C * 4;
            for (int i = gid; i < n; i += stride) {
                int kp4 = i / c4;
                int rem = i - kp4 * c4;
                int c = rem >> 2, ki = rem & 3;
                int kp = kp4 * 4 + ki;
                d[i] = pack2(s[(2 * kp) * C + c], s[(2 * kp + 1) * C + c]);
            }
        };
        packmat(P.q_w, 128, 128, P.wH + OFF_Q);
        packmat(P.k_w, 128, 128, P.wH + OFF_K);
        packmat(P.v_w, 128, 128, P.wH + OFF_V);
        packmat(P.o_w, 128, 128, P.wH + OFF_O);
        packmat(P.l1_w, 128, 256, P.wH + OFF_L1);
        packmat(P.l2_w, 256, 128, P.wH + OFF_L2);
        packmat(P.in_w, 64, 128, P.wH + OFF_IN);
        packmat(P.pe_w2, 64, 128, P.wH + OFF_PE);
        packmat(P.fu_w, 192, 64, P.wH + OFF_FU);
        if (gid < 128) P.bnSum[gid] = 0.f;    // bnSum..bnSq contiguous 128
    }
    __threadfence();
    grid.sync();

    float accS[2][4];   // per-tile src rows, kept in registers for phase 2

    // ================= phase 1: src+qkv, then nbr; 2 tiles per block =======
#pragma unroll
    for (int t = 0; t < 2; ++t) {
        const int r0 = (bx + t * 512) * 8;
        __syncthreads();                  // LDS reuse guard between tiles

        // ---- phase 1a: src + q/k/v projections ---------------------------
        if (tid < 24) U.ka.sC[tid] = P.coords[r0 * 3 + tid];
        {   // features 8x64 -> packed pairs
            float2 f = *(const float2*)(P.features + r0 * 64 + tid * 2);
            U.ka.FHp[tid] = pack2(f.x, f.y);
        }
        __syncthreads();
        {   // pe hidden, 2 cols per thread, packed
            int r = tid >> 5, t2 = (tid & 31) * 2;
            float v0 = U.ka.sC[r * 3 + 0] * (1.f / 95.f);
            float v1 = U.ka.sC[r * 3 + 1] * (1.f / 95.f);
            float v2 = U.ka.sC[r * 3 + 2] * (1.f / 95.f);
            float h0 = v0 * P.pe_w1[t2] + v1 * P.pe_w1[64 + t2] + v2 * P.pe_w1[128 + t2] + P.pe_b1[t2];
            float h1 = v0 * P.pe_w1[t2 + 1] + v1 * P.pe_w1[64 + t2 + 1] + v2 * P.pe_w1[128 + t2 + 1] + P.pe_b1[t2 + 1];
            U.ka.HHp[tid] = pack2(relu(h0), relu(h1));
        }
        __syncthreads();
        const int c = tid & 127, rh = tid >> 7;
        {
            const unsigned* inH = P.wH + OFF_IN + c * 4;   // + kp4*512
            const unsigned* peH = P.wH + OFF_PE + c * 4;
            float acc[4];
            const float base = P.in_b[c] + P.pe_b2[c];
#pragma unroll
            for (int r = 0; r < 4; ++r) acc[r] = base;
            for (int kp4 = 0; kp4 < 8; ++kp4) {
                uint4 wi = *(const uint4*)(inH + kp4 * 512);
                uint4 wp = *(const uint4*)(peH + kp4 * 512);
#pragma unroll
                for (int r = 0; r < 4; ++r) {
                    const int rr = rh * 4 + r;
                    uint4 f = *(const uint4*)(&U.ka.FHp[rr * 32 + kp4 * 4]);
                    uint4 h = *(const uint4*)(&U.ka.HHp[rr * 32 + kp4 * 4]);
                    acc[r] = dot2(f.x, wi.x, acc[r]); acc[r] = dot2(f.y, wi.y, acc[r]);
                    acc[r] = dot2(f.z, wi.z, acc[r]); acc[r] = dot2(f.w, wi.w, acc[r]);
                    acc[r] = dot2(h.x, wp.x, acc[r]); acc[r] = dot2(h.y, wp.y, acc[r]);
                    acc[r] = dot2(h.z, wp.z, acc[r]); acc[r] = dot2(h.w, wp.w, acc[r]);
                }
            }
#pragma unroll
            for (int r = 0; r < 4; ++r) {
                U.ka.S[(rh * 4 + r) * 128 + c] = acc[r];
                accS[t][r] = acc[r];
            }
        }
        __syncthreads();
        for (int i = tid; i < 512; i += 256) {
            float2 s = *(const float2*)(&U.ka.S[i * 2]);
            U.ka.SH[i] = pack2(s.x, s.y);
        }
        __syncthreads();
        {
            const unsigned* qH = P.wH + OFF_Q + c * 4;   // + kp4*512
            const unsigned* kH = P.wH + OFF_K + c * 4;
            const unsigned* vH = P.wH + OFF_V + c * 4;
            float aq[4], ak[4], av[4];
#pragma unroll
            for (int r = 0; r < 4; ++r) { aq[r] = 0.f; ak[r] = 0.f; av[r] = 0.f; }
            for (int kp4 = 0; kp4 < 16; ++kp4) {
                uint4 wq = *(const uint4*)(qH + kp4 * 512);
                uint4 wk = *(const uint4*)(kH + kp4 * 512);
                uint4 wv = *(const uint4*)(vH + kp4 * 512);
#pragma unroll
                for (int r = 0; r < 4; ++r) {
                    uint4 s4 = *(const uint4*)(&U.ka.SH[(rh * 4 + r) * 64 + kp4 * 4]);
                    aq[r] = dot2(s4.x, wq.x, aq[r]); aq[r] = dot2(s4.y, wq.y, aq[r]);
                    aq[r] = dot2(s4.z, wq.z, aq[r]); aq[r] = dot2(s4.w, wq.w, aq[r]);
                    ak[r] = dot2(s4.x, wk.x, ak[r]); ak[r] = dot2(s4.y, wk.y, ak[r]);
                    ak[r] = dot2(s4.z, wk.z, ak[r]); ak[r] = dot2(s4.w, wk.w, ak[r]);
                    av[r] = dot2(s4.x, wv.x, av[r]); av[r] = dot2(s4.y, wv.y, av[r]);
                    av[r] = dot2(s4.z, wv.z, av[r]); av[r] = dot2(s4.w, wv.w, av[r]);
                }
            }
#pragma unroll
            for (int r = 0; r < 4; ++r) {
                P.qs[(r0 + rh * 4 + r) * 128 + c] = aq[r];
                P.ks[(r0 + rh * 4 + r) * 128 + c] = ak[r];
                P.vs[(r0 + rh * 4 + r) * 128 + c] = av[r];
            }
        }

        // ---- phase 1b: neighbor top-16 for rows r0..r0+7 -----------------
        if (tid < 8) U.ka.cnt[tid] = 0;
        if (tid < 128) U.ka.outL[tid] = -1;
        __syncthreads();
        {
            int qx[8], qy[8], qz[8];
#pragma unroll
            for (int q = 0; q < 8; ++q) {
                qx[q] = P.coords[(r0 + q) * 3 + 0];
                qy[q] = P.coords[(r0 + q) * 3 + 1];
                qz[q] = P.coords[(r0 + q) * 3 + 2];
            }
            for (int cd = tid; cd < P.N; cd += 256) {
                int cx = P.coords[cd * 3 + 0];
                int cy = P.coords[cd * 3 + 1];
                int cz = P.coords[cd * 3 + 2];
#pragma unroll
                for (int q = 0; q < 8; ++q) {
                    int dx = cx - qx[q]; dx = dx < 0 ? -dx : dx;
                    int dy = cy - qy[q]; dy = dy < 0 ? -dy : dy;
                    int dz = cz - qz[q]; dz = dz < 0 ? -dz : dz;
                    int d = dx + dy + dz;
                    if (d <= 4) {
                        int s = atomicAdd(&U.ka.cnt[q], 1);
                        if (s < 64) U.ka.lst[q * 64 + s] = (d << 13) | cd;
                    }
                }
            }
        }
        __syncthreads();
        {
            const int q = tid >> 5, tt = tid & 31;
            int n = U.ka.cnt[q]; if (n > 64) n = 64;
            for (int e = tt; e < n; e += 32) {
                int key = U.ka.lst[q * 64 + e];
                int rank = 0;
                for (int j = 0; j < n; ++j) rank += (U.ka.lst[q * 64 + j] < key) ? 1 : 0;
                if (rank < 16) U.ka.outL[q * 16 + rank] = key & 8191;
            }
        }
        __syncthreads();
        if (tid < 128) {
            int q = tid >> 4, tt = tid & 15;
            P.nbr[(r0 + q) * 16 + tt] = U.ka.outL[tid];
        }
    }
    __threadfence();
    grid.sync();

    float accF[2][2];   // per-tile fused rows, kept for final BN

    // ================= phase 2: attention + FFN + fusion; 2 tiles ==========
#pragma unroll
    for (int t = 0; t < 2; ++t) {
        const int r0 = (bx + t * 512) * 8;
        __syncthreads();                  // LDS reuse guard

#pragma unroll
        for (int r = 0; r < 4; ++r)
            U.k4.A[((tid >> 7) * 4 + r) * 128 + (tid & 127)] = accS[t][r];
        {
            float2 f = *(const float2*)(P.features + r0 * 64 + tid * 2);
            U.k4.FH[tid] = pack2(f.x, f.y);
        }
        if (tid < 128) {
            U.k4.idxL[tid] = P.nbr[r0 * 16 + tid];
            U.k4.bK[tid] = P.k_b[tid]; U.k4.bV[tid] = P.v_b[tid];
        }
        __syncthreads();
        {   // Q gather + bias
            int r = tid >> 5, cg2 = tid & 31;
            int i0 = U.k4.idxL[r * 16];
            float4 qv = make_float4(0.f, 0.f, 0.f, 0.f);
            if (i0 >= 0) qv = *(const float4*)(P.qs + i0 * 128 + cg2 * 4);
            float4 qb = *(const float4*)(P.q_b + cg2 * 4);
            qv.x += qb.x; qv.y += qb.y; qv.z += qb.z; qv.w += qb.w;
            *(float4*)(&U.k4.Q[r * 128 + cg2 * 4]) = qv;
        }
        __syncthreads();

        // ---- scores; q.kb hoisted ----------------------------------------
        const int ar = tid >> 5, ah = (tid >> 3) & 3, ag = tid & 7;
        {
            const int ch = ag & 3;
            float sbias = 0.f;
#pragma unroll
            for (int c4 = 0; c4 < 8; ++c4) {
                float4 qv = *(const float4*)(&U.k4.Q[ar * 128 + ah * 32 + c4 * 4]);
                float4 kb = *(const float4*)(&U.k4.bK[ch * 32 + c4 * 4]);
                sbias += qv.x * kb.x + qv.y * kb.y + qv.z * kb.z + qv.w * kb.w;
            }
#pragma unroll
            for (int jj = 0; jj < 2; ++jj) {
                int j = ag + jj * 8;
                int j4 = j >> 2;
                int id = U.k4.idxL[ar * 16 + ah * 4 + j4];
                float s = 0.f;
                if (id >= 0) {
#pragma unroll
                    for (int c4 = 0; c4 < 8; ++c4) {
                        float4 qv = *(const float4*)(&U.k4.Q[ar * 128 + ah * 32 + c4 * 4]);
                        float4 kv = *(const float4*)(P.ks + id * 128 + ch * 32 + c4 * 4);
                        s += qv.x * kv.x + qv.y * kv.y + qv.z * kv.z + qv.w * kv.w;
                    }
                }
                U.k4.SC[ar * 64 + ah * 16 + j] = (s + sbias) * 0.08838834764831845f;
            }
        }
        __syncthreads();

        // ---- softmax + P@V (sum w = 1 => +vb once); packed write ---------
        {
            float p[16];
            float mx = -3.4e38f;
#pragma unroll
            for (int j = 0; j < 16; ++j) { p[j] = U.k4.SC[ar * 64 + ah * 16 + j]; mx = fmaxf(mx, p[j]); }
            float sum = 0.f;
#pragma unroll
            for (int j = 0; j < 16; ++j) { p[j] = __expf(p[j] - mx); sum += p[j]; }
            float inv = 1.f / sum;
            float4 acc = make_float4(0.f, 0.f, 0.f, 0.f);
#pragma unroll
            for (int j = 0; j < 16; ++j) {
                int j4 = j >> 2, ch = j & 3;
                int id = U.k4.idxL[ar * 16 + ah * 4 + j4];
                float w = p[j] * inv;
                if (id >= 0) {
                    float4 vv = *(const float4*)(P.vs + id * 128 + ch * 32 + ag * 4);
                    acc.x += w * vv.x; acc.y += w * vv.y;
                    acc.z += w * vv.z; acc.w += w * vv.w;
                }
            }
            float4 vb = *(const float4*)(&U.k4.bV[ah * 32 + ag * 4]);
            acc.x += vb.x; acc.y += vb.y; acc.z += vb.z; acc.w += vb.w;
            U.k4.BtH[ar * 64 + ah * 16 + ag * 2]     = pack2(acc.x, acc.y);
            U.k4.BtH[ar * 64 + ah * 16 + ag * 2 + 1] = pack2(acc.z, acc.w);
        }
        __syncthreads();

        // ---- o-proj: C = A + head_out @ o_w + o_b ------------------------
        {
            const int c = tid & 127, rh = tid >> 7;
            const unsigned* oH = P.wH + OFF_O + c * 4;
            float acc[4];
#pragma unroll
            for (int r = 0; r < 4; ++r) acc[r] = 0.f;
            for (int kp4 = 0; kp4 < 16; ++kp4) {
                uint4 w = *(const uint4*)(oH + kp4 * 512);
#pragma unroll
                for (int r = 0; r < 4; ++r) {
                    uint4 tt = *(const uint4*)(&U.k4.BtH[(rh * 4 + r) * 64 + kp4 * 4]);
                    acc[r] = dot2(tt.x, w.x, acc[r]); acc[r] = dot2(tt.y, w.y, acc[r]);
                    acc[r] = dot2(tt.z, w.z, acc[r]); acc[r] = dot2(tt.w, w.w, acc[r]);
                }
            }
            const float ob = P.o_b[c];
#pragma unroll
            for (int r = 0; r < 4; ++r) {
                const int rr = rh * 4 + r;
                U.k4.C[rr * 128 + c] = U.k4.A[rr * 128 + c] + ob + acc[r];
            }
        }
        __syncthreads();
        {   // LN1 (+ pack into CH)
            const int r = tid >> 5, l = tid & 31;
            float x[4]; float s = 0.f, s2 = 0.f;
#pragma unroll
            for (int i = 0; i < 4; ++i) {
                x[i] = U.k4.C[r * 128 + l * 4 + i];
                s += x[i]; s2 += x[i] * x[i];
            }
#pragma unroll
            for (int o = 1; o < 32; o <<= 1) { s += __shfl_xor(s, o); s2 += __shfl_xor(s2, o); }
            float mu = s * (1.f / 128.f);
            float var = s2 * (1.f / 128.f) - mu * mu;
            float rstd = rsqrtf(var + 1e-5f);
            float y[4];
#pragma unroll
            for (int i = 0; i < 4; ++i) {
                int cc = l * 4 + i;
                y[i] = (x[i] - mu) * rstd * P.n1_g[cc] + P.n1_b[cc];
                U.k4.C[r * 128 + cc] = y[i];
            }
            U.k4.CH[r * 64 + l * 2]     = pack2(y[0], y[1]);
            U.k4.CH[r * 64 + l * 2 + 1] = pack2(y[2], y[3]);
        }
        __syncthreads();

        // ---- FFN-1: Hh = relu(CH @ l1_w + l1_b) --------------------------
        {
            const int f = tid;
            const unsigned* l1H = P.wH + OFF_L1 + f * 4;
            float acc[8];
#pragma unroll
            for (int r = 0; r < 8; ++r) acc[r] = 0.f;
            for (int kp4 = 0; kp4 < 16; ++kp4) {
                uint4 w = *(const uint4*)(l1H + kp4 * 1024);
#pragma unroll
                for (int r = 0; r < 8; ++r) {
                    uint4 tt = *(const uint4*)(&U.k4.CH[r * 64 + kp4 * 4]);
                    acc[r] = dot2(tt.x, w.x, acc[r]); acc[r] = dot2(tt.y, w.y, acc[r]);
                    acc[r] = dot2(tt.z, w.z, acc[r]); acc[r] = dot2(tt.w, w.w, acc[r]);
                }
            }
            const float bb = P.l1_b[f];
#pragma unroll
            for (int r = 0; r < 8; ++r) U.k4.Hh[r * 256 + f] = (_Float16)relu(acc[r] + bb);
        }
        __syncthreads();

        // ---- FFN-2: C += Hh @ l2_w + l2_b --------------------------------
        {
            const int c = tid & 127, rh = tid >> 7;
            const unsigned* l2H = P.wH + OFF_L2 + c * 4;
            const unsigned* HhU = (const unsigned*)U.k4.Hh;
            float acc[4];
#pragma unroll
            for (int r = 0; r < 4; ++r) acc[r] = 0.f;
            for (int kp4 = 0; kp4 < 32; ++kp4) {
                uint4 w = *(const uint4*)(l2H + kp4 * 512);
#pragma unroll
                for (int r = 0; r < 4; ++r) {
                    uint4 tt = *(const uint4*)(&HhU[(rh * 4 + r) * 128 + kp4 * 4]);
                    acc[r] = dot2(tt.x, w.x, acc[r]); acc[r] = dot2(tt.y, w.y, acc[r]);
                    acc[r] = dot2(tt.z, w.z, acc[r]); acc[r] = dot2(tt.w, w.w, acc[r]);
                }
            }
            const float lb = P.l2_b[c];
#pragma unroll
            for (int r = 0; r < 4; ++r) {
                const int rr = rh * 4 + r;
                U.k4.C[rr * 128 + c] += lb + acc[r];
            }
        }
        __syncthreads();
        {   // LN2 (+ pack into CH)
            const int r = tid >> 5, l = tid & 31;
            float x[4]; float s = 0.f, s2 = 0.f;
#pragma unroll
            for (int i = 0; i < 4; ++i) {
                x[i] = U.k4.C[r * 128 + l * 4 + i];
                s += x[i]; s2 += x[i] * x[i];
            }
#pragma unroll
            for (int o = 1; o < 32; o <<= 1) { s += __shfl_xor(s, o); s2 += __shfl_xor(s2, o); }
            float mu = s * (1.f / 128.f);
            float var = s2 * (1.f / 128.f) - mu * mu;
            float rstd = rsqrtf(var + 1e-5f);
            float y[4];
#pragma unroll
            for (int i = 0; i < 4; ++i) {
                int cc = l * 4 + i;
                y[i] = (x[i] - mu) * rstd * P.n3_g[cc] + P.n3_b[cc];
                U.k4.C[r * 128 + cc] = y[i];
            }
            U.k4.CH[r * 64 + l * 2]     = pack2(y[0], y[1]);
            U.k4.CH[r * 64 + l * 2 + 1] = pack2(y[2], y[3]);
        }
        __syncthreads();

        // ---- fusion: fused = [F, C] @ fu_w + fu_b; BN partials -----------
        {
            const int c = tid & 63, rg = tid >> 6;
            const unsigned* fuH = P.wH + OFF_FU + c * 4;
            float acc[2];
            const float fb = P.fu_b[c];
#pragma unroll
            for (int r = 0; r < 2; ++r) acc[r] = fb;
            for (int kp4 = 0; kp4 < 8; ++kp4) {
                uint4 w = *(const uint4*)(fuH + kp4 * 256);
#pragma unroll
                for (int r = 0; r < 2; ++r) {
                    uint4 tt = *(const uint4*)(&U.k4.FH[(rg * 2 + r) * 32 + kp4 * 4]);
                    acc[r] = dot2(tt.x, w.x, acc[r]); acc[r] = dot2(tt.y, w.y, acc[r]);
                    acc[r] = dot2(tt.z, w.z, acc[r]); acc[r] = dot2(tt.w, w.w, acc[r]);
                }
            }
            for (int kp4 = 0; kp4 < 16; ++kp4) {
                uint4 w = *(const uint4*)(fuH + (8 + kp4) * 256);
#pragma unroll
                for (int r = 0; r < 2; ++r) {
                    uint4 tt = *(const uint4*)(&U.k4.CH[(rg * 2 + r) * 64 + kp4 * 4]);
                    acc[r] = dot2(tt.x, w.x, acc[r]); acc[r] = dot2(tt.y, w.y, acc[r]);
                    acc[r] = dot2(tt.z, w.z, acc[r]); acc[r] = dot2(tt.w, w.w, acc[r]);
                }
            }
#pragma unroll
            for (int r = 0; r < 2; ++r) {
                int row = rg * 2 + r;
                U.k4.A[row * 64 + c] = acc[r];
                accF[t][r] = acc[r];
            }
        }
        __syncthreads();
        if (tid < 64) {
            float s = 0.f, s2 = 0.f;
#pragma unroll
            for (int r = 0; r < 8; ++r) { float x = U.k4.A[r * 64 + tid]; s += x; s2 += x * x; }
            atomicAdd(&P.bnSum[tid], s);
            atomicAdd(&P.bnSq[tid], s2);
        }
    }
    __threadfence();
    grid.sync();

    // ================= phase 3: batchnorm + relu -> out ====================
    {
        const int c = tid & 63, rg = tid >> 6;
        const float invN = 1.f / (float)P.N;
        float mu = P.bnSum[c] * invN;
        float var = P.bnSq[c] * invN - mu * mu;
        float rstd = rsqrtf(var + 1e-3f);
        float gg = P.bn_g[c], bb = P.bn_b[c];
#pragma unroll
        for (int t = 0; t < 2; ++t) {
            const int r0 = (bx + t * 512) * 8;
#pragma unroll
            for (int r = 0; r < 2; ++r) {
                float y = (accF[t][r] - mu) * rstd * gg + bb;
                P.out[(r0 + rg * 2 + r) * 64 + c] = relu(y);
            }
        }
    }
}

// ===========================================================================
// FALLBACK PATH: round-8 4-kernel pipeline (verbatim; absmax 0.0156, 207us).
// Used if the cooperative launch is rejected by the runtime.
// ===========================================================================
__global__ __launch_bounds__(256) void k0_pack(
    const float* __restrict__ q_w, const float* __restrict__ k_w,
    const float* __restrict__ v_w, const float* __restrict__ o_w,
    const float* __restrict__ l1_w, const float* __restrict__ l2_w,
    const float* __restrict__ in_w, const float* __restrict__ pe_w2,
    const float* __restrict__ fu_w, unsigned* __restrict__ dst)
{
    const int gid = blockIdx.x * 256 + threadIdx.x;
    const int stride = gridDim.x * 256;
    auto packmat = [&](const float* s, int K, int C, unsigned* d) {
        const int kp2 = K / 2;
        const int n = kp2 * C;
        const int c4 = C * 4;
        for (int i = gid; i < n; i += stride) {
            int kp4 = i / c4;
            int rem = i - kp4 * c4;
            int c = rem >> 2, ki = rem & 3;
            int kp = kp4 * 4 + ki;
            d[i] = pack2(s[(2 * kp) * C + c], s[(2 * kp + 1) * C + c]);
        }
    };
    packmat(q_w, 128, 128, dst + OFF_Q);
    packmat(k_w, 128, 128, dst + OFF_K);
    packmat(v_w, 128, 128, dst + OFF_V);
    packmat(o_w, 128, 128, dst + OFF_O);
    packmat(l1_w, 128, 256, dst + OFF_L1);
    packmat(l2_w, 256, 128, dst + OFF_L2);
    packmat(in_w, 64, 128, dst + OFF_IN);
    packmat(pe_w2, 64, 128, dst + OFF_PE);
    packmat(fu_w, 192, 64, dst + OFF_FU);
}

__global__ __launch_bounds__(256, 4) void ka_pre_cst(
    const float* __restrict__ features, const int* __restrict__ coords,
    const float* __restrict__ pe_w1, const float* __restrict__ pe_b1,
    const float* __restrict__ pe_b2,
    const float* __restrict__ in_b,
    const unsigned* __restrict__ wH,
    float* __restrict__ src,
    float* __restrict__ qs, float* __restrict__ ks, float* __restrict__ vs,
    int* __restrict__ nbr, float* __restrict__ bnAcc, int N)
{
    __shared__ __align__(16) float S[1024];
    __shared__ __align__(16) unsigned SH[512];
    __shared__ __align__(16) unsigned FHp[256];
    __shared__ __align__(16) unsigned HHp[256];
    __shared__ int   sC[24];
    __shared__ int cnt[16];
    __shared__ int lst[16 * 64];
    __shared__ int outL[256];

    const int tid = threadIdx.x;
    const int bx = blockIdx.x;
    const int role_nbr = (bx % 3) == 2;

    if (role_nbr) {
        const int nb = bx / 3;
        const int q0 = nb * 16;
        if (nb == 0 && tid < 128) bnAcc[tid] = 0.f;
        if (tid < 16) cnt[tid] = 0;
        outL[tid] = -1;
        __syncthreads();
        int qx[16], qy[16], qz[16];
#pragma unroll
        for (int q = 0; q < 16; ++q) {
            qx[q] = coords[(q0 + q) * 3 + 0];
            qy[q] = coords[(q0 + q) * 3 + 1];
            qz[q] = coords[(q0 + q) * 3 + 2];
        }
        for (int cd = tid; cd < N; cd += 256) {
            int cx = coords[cd * 3 + 0];
            int cy = coords[cd * 3 + 1];
            int cz = coords[cd * 3 + 2];
#pragma unroll
            for (int q = 0; q < 16; ++q) {
                int dx = cx - qx[q]; dx = dx < 0 ? -dx : dx;
                int dy = cy - qy[q]; dy = dy < 0 ? -dy : dy;
                int dz = cz - qz[q]; dz = dz < 0 ? -dz : dz;
                int d = dx + dy + dz;
                if (d <= 4) {
                    int s = atomicAdd(&cnt[q], 1);
                    if (s < 64) lst[q * 64 + s] = (d << 13) | cd;
                }
            }
        }
        __syncthreads();
        {
            const int q = tid >> 4, t = tid & 15;
            int n = cnt[q]; if (n > 64) n = 64;
            for (int e = t; e < n; e += 16) {
                int key = lst[q * 64 + e];
                int rank = 0;
                for (int j = 0; j < n; ++j) rank += (lst[q * 64 + j] < key) ? 1 : 0;
                if (rank < 16) outL[q * 16 + rank] = key & 8191;
            }
        }
        __syncthreads();
        {
            const int q = tid >> 4, t = tid & 15;
            nbr[(q0 + q) * 16 + t] = outL[q * 16 + t];
        }
        return;
    }

    const int sb = (bx / 3) * 2 + (bx % 3);
    const int r0 = sb * 8;
    if (tid < 24) sC[tid] = coords[r0 * 3 + tid];
    if (tid < 256) {
        float2 f = *(const float2*)(features + r0 * 64 + tid * 2);
        FHp[tid] = pack2(f.x, f.y);
    }
    __syncthreads();
    if (tid < 256) {
        int r = tid >> 5, t2 = (tid & 31) * 2;
        float v0 = sC[r * 3 + 0] * (1.f / 95.f);
        float v1 = sC[r * 3 + 1] * (1.f / 95.f);
        float v2 = sC[r * 3 + 2] * (1.f / 95.f);
        float h0 = v0 * pe_w1[t2] + v1 * pe_w1[64 + t2] + v2 * pe_w1[128 + t2] + pe_b1[t2];
        float h1 = v0 * pe_w1[t2 + 1] + v1 * pe_w1[64 + t2 + 1] + v2 * pe_w1[128 + t2 + 1] + pe_b1[t2 + 1];
        HHp[tid] = pack2(relu(h0), relu(h1));
    }
    __syncthreads();
    const int c = tid & 127, rh = tid >> 7;
    {
        const unsigned* inH = wH + OFF_IN + c * 4;
        const unsigned* peH = wH + OFF_PE + c * 4;
        float acc[4];
        const float base = in_b[c] + pe_b2[c];
#pragma unroll
        for (int r = 0; r < 4; ++r) acc[r] = base;
        for (int kp4 = 0; kp4 < 8; ++kp4) {
            uint4 wi = *(const uint4*)(inH + kp4 * 512);
            uint4 wp = *(const uint4*)(peH + kp4 * 512);
#pragma unroll
            for (int r = 0; r < 4; ++r) {
                const int rr = rh * 4 + r;
                uint4 f = *(const uint4*)(&FHp[rr * 32 + kp4 * 4]);
                uint4 h = *(const uint4*)(&HHp[rr * 32 + kp4 * 4]);
                acc[r] = dot2(f.x, wi.x, acc[r]); acc[r] = dot2(f.y, wi.y, acc[r]);
                acc[r] = dot2(f.z, wi.z, acc[r]); acc[r] = dot2(f.w, wi.w, acc[r]);
                acc[r] = dot2(h.x, wp.x, acc[r]); acc[r] = dot2(h.y, wp.y, acc[r]);
                acc[r] = dot2(h.z, wp.z, acc[r]); acc[r] = dot2(h.w, wp.w, acc[r]);
            }
        }
#pragma unroll
        for (int r = 0; r < 4; ++r) {
            src[(r0 + rh * 4 + r) * 128 + c] = acc[r];
            S[(rh * 4 + r) * 128 + c] = acc[r];
        }
    }
    __syncthreads();
    for (int i = tid; i < 512; i += 256) {
        float2 s = *(const float2*)(&S[i * 2]);
        SH[i] = pack2(s.x, s.y);
    }
    __syncthreads();
    {
        const unsigned* qH = wH + OFF_Q + c * 4;
        const unsigned* kH = wH + OFF_K + c * 4;
        const unsigned* vH = wH + OFF_V + c * 4;
        float aq[4], ak[4], av[4];
#pragma unroll
        for (int r = 0; r < 4; ++r) { aq[r] = 0.f; ak[r] = 0.f; av[r] = 0.f; }
        for (int kp4 = 0; kp4 < 16; ++kp4) {
            uint4 wq = *(const uint4*)(qH + kp4 * 512);
            uint4 wk = *(const uint4*)(kH + kp4 * 512);
            uint4 wv = *(const uint4*)(vH + kp4 * 512);
#pragma unroll
            for (int r = 0; r < 4; ++r) {
                uint4 s4 = *(const uint4*)(&SH[(rh * 4 + r) * 64 + kp4 * 4]);
                aq[r] = dot2(s4.x, wq.x, aq[r]); aq[r] = dot2(s4.y, wq.y, aq[r]);
                aq[r] = dot2(s4.z, wq.z, aq[r]); aq[r] = dot2(s4.w, wq.w, aq[r]);
                ak[r] = dot2(s4.x, wk.x, ak[r]); ak[r] = dot2(s4.y, wk.y, ak[r]);
                ak[r] = dot2(s4.z, wk.z, ak[r]); ak[r] = dot2(s4.w, wk.w, ak[r]);
                av[r] = dot2(s4.x, wv.x, av[r]); av[r] = dot2(s4.y, wv.y, av[r]);
                av[r] = dot2(s4.z, wv.z, av[r]); av[r] = dot2(s4.w, wv.w, av[r]);
            }
        }
#pragma unroll
        for (int r = 0; r < 4; ++r) {
            qs[(r0 + rh * 4 + r) * 128 + c] = aq[r];
            ks[(r0 + rh * 4 + r) * 128 + c] = ak[r];
            vs[(r0 + rh * 4 + r) * 128 + c] = av[r];
        }
    }
}

DEVFN void ln_rows8_pack(float* Cb, unsigned* CHp, const float* __restrict__ g,
                         const float* __restrict__ b, int tid)
{
    const int r = tid >> 5, l = tid & 31;
    float x[4]; float s = 0.f, s2 = 0.f;
#pragma unroll
    for (int i = 0; i < 4; ++i) {
        x[i] = Cb[r * 128 + l * 4 + i];
        s += x[i]; s2 += x[i] * x[i];
    }
#pragma unroll
    for (int o = 1; o < 32; o <<= 1) { s += __shfl_xor(s, o); s2 += __shfl_xor(s2, o); }
    float mu = s * (1.f / 128.f);
    float var = s2 * (1.f / 128.f) - mu * mu;
    float rstd = rsqrtf(var + 1e-5f);
    float y[4];
#pragma unroll
    for (int i = 0; i < 4; ++i) {
        int cc = l * 4 + i;
        y[i] = (x[i] - mu) * rstd * g[cc] + b[cc];
        Cb[r * 128 + cc] = y[i];
    }
    CHp[r * 64 + l * 2]     = pack2(y[0], y[1]);
    CHp[r * 64 + l * 2 + 1] = pack2(y[2], y[3]);
}

__global__ __launch_bounds__(256, 4) void k4_main_cst(
    const float* __restrict__ features, const float* __restrict__ src,
    const float* __restrict__ qs, const float* __restrict__ ks, const float* __restrict__ vs,
    const int* __restrict__ nbr,
    const float* __restrict__ q_b, const float* __restrict__ k_b,
    const float* __restrict__ v_b,
    const unsigned* __restrict__ wH,
    const float* __restrict__ o_b,
    const float* __restrict__ n1_g, const float* __restrict__ n1_b,
    const float* __restrict__ l1_b,
    const float* __restrict__ l2_b,
    const float* __restrict__ n3_g, const float* __restrict__ n3_b,
    const float* __restrict__ fu_b,
    float* __restrict__ fused, float* __restrict__ bnSum, float* __restrict__ bnSq)
{
    __shared__ __align__(16) float A[1024];
    __shared__ __align__(16) float C[1024];
    __shared__ __align__(16) float Q[1024];
    __shared__ __align__(16) float SC[512];
    __shared__ __align__(16) unsigned BtH[512];
    __shared__ __align__(16) unsigned CH[512];
    __shared__ __align__(16) unsigned FH[256];
    __shared__ __align__(16) _Float16 Hh[2048];
    __shared__ __align__(16) float bK[128], bV[128];
    __shared__ int idxL[128];
    const int tid = threadIdx.x;
    const int r0 = blockIdx.x * 8;

    for (int i = tid; i < 1024; i += 256) A[i] = src[r0 * 128 + i];
    if (tid < 256) {
        float2 f = *(const float2*)(features + r0 * 64 + tid * 2);
        FH[tid] = pack2(f.x, f.y);
    }
    if (tid < 128) {
        idxL[tid] = nbr[r0 * 16 + tid];
        bK[tid] = k_b[tid]; bV[tid] = v_b[tid];
    }
    __syncthreads();
    {
        int r = tid >> 5, cg = tid & 31;
        int i0 = idxL[r * 16];
        float4 qv = make_float4(0.f, 0.f, 0.f, 0.f);
        if (i0 >= 0) qv = *(const float4*)(qs + i0 * 128 + cg * 4);
        float4 qb = *(const float4*)(q_b + cg * 4);
        qv.x += qb.x; qv.y += qb.y; qv.z += qb.z; qv.w += qb.w;
        *(float4*)(&Q[r * 128 + cg * 4]) = qv;
    }
    __syncthreads();

    const int ar = tid >> 5, ah = (tid >> 3) & 3, ag = tid & 7;
    {
        const int ch = ag & 3;
        float sbias = 0.f;
#pragma unroll
        for (int c4 = 0; c4 < 8; ++c4) {
            float4 qv = *(const float4*)(&Q[ar * 128 + ah * 32 + c4 * 4]);
            float4 kb = *(const float4*)(&bK[ch * 32 + c4 * 4]);
            sbias += qv.x * kb.x + qv.y * kb.y + qv.z * kb.z + qv.w * kb.w;
        }
#pragma unroll
        for (int jj = 0; jj < 2; ++jj) {
            int j = ag + jj * 8;
            int j4 = j >> 2;
            int id = idxL[ar * 16 + ah * 4 + j4];
            float s = 0.f;
            if (id >= 0) {
#pragma unroll
                for (int c4 = 0; c4 < 8; ++c4) {
                    float4 qv = *(const float4*)(&Q[ar * 128 + ah * 32 + c4 * 4]);
                    float4 kv = *(const float4*)(ks + id * 128 + ch * 32 + c4 * 4);
                    s += qv.x * kv.x + qv.y * kv.y + qv.z * kv.z + qv.w * kv.w;
                }
            }
            SC[ar * 64 + ah * 16 + j] = (s + sbias) * 0.08838834764831845f;
        }
    }
    __syncthreads();

    {
        float p[16];
        float mx = -3.4e38f;
#pragma unroll
        for (int j = 0; j < 16; ++j) { p[j] = SC[ar * 64 + ah * 16 + j]; mx = fmaxf(mx, p[j]); }
        float sum = 0.f;
#pragma unroll
        for (int j = 0; j < 16; ++j) { p[j] = __expf(p[j] - mx); sum += p[j]; }
        float inv = 1.f / sum;
        float4 acc = make_float4(0.f, 0.f, 0.f, 0.f);
#pragma unroll
        for (int j = 0; j < 16; ++j) {
            int j4 = j >> 2, ch = j & 3;
            int id = idxL[ar * 16 + ah * 4 + j4];
            float w = p[j] * inv;
            if (id >= 0) {
                float4 vv = *(const float4*)(vs + id * 128 + ch * 32 + ag * 4);
                acc.x += w * vv.x; acc.y += w * vv.y;
                acc.z += w * vv.z; acc.w += w * vv.w;
            }
        }
        float4 vb = *(const float4*)(&bV[ah * 32 + ag * 4]);
        acc.x += vb.x; acc.y += vb.y; acc.z += vb.z; acc.w += vb.w;
        BtH[ar * 64 + ah * 16 + ag * 2]     = pack2(acc.x, acc.y);
        BtH[ar * 64 + ah * 16 + ag * 2 + 1] = pack2(acc.z, acc.w);
    }
    __syncthreads();

    {
        const int c = tid & 127, rh = tid >> 7;
        const unsigned* oH = wH + OFF_O + c * 4;
        float acc[4];
#pragma unroll
        for (int r = 0; r < 4; ++r) acc[r] = 0.f;
        for (int kp4 = 0; kp4 < 16; ++kp4) {
            uint4 w = *(const uint4*)(oH + kp4 * 512);
#pragma unroll
            for (int r = 0; r < 4; ++r) {
                uint4 t = *(const uint4*)(&BtH[(rh * 4 + r) * 64 + kp4 * 4]);
                acc[r] = dot2(t.x, w.x, acc[r]); acc[r] = dot2(t.y, w.y, acc[r]);
                acc[r] = dot2(t.z, w.z, acc[r]); acc[r] = dot2(t.w, w.w, acc[r]);
            }
        }
        const float ob = o_b[c];
#pragma unroll
        for (int r = 0; r < 4; ++r) {
            const int rr = rh * 4 + r;
            C[rr * 128 + c] = A[rr * 128 + c] + ob + acc[r];
        }
    }
    __syncthreads();
    ln_rows8_pack(C, CH, n1_g, n1_b, tid);
    __syncthreads();

    {
        const int f = tid;
        const unsigned* l1H = wH + OFF_L1 + f * 4;
        float acc[8];
#pragma unroll
        for (int r = 0; r < 8; ++r) acc[r] = 0.f;
        for (int kp4 = 0; kp4 < 16; ++kp4) {
            uint4 w = *(const uint4*)(l1H + kp4 * 1024);
#pragma unroll
            for (int r = 0; r < 8; ++r) {
                uint4 t = *(const uint4*)(&CH[r * 64 + kp4 * 4]);
                acc[r] = dot2(t.x, w.x, acc[r]); acc[r] = dot2(t.y, w.y, acc[r]);
                acc[r] = dot2(t.z, w.z, acc[r]); acc[r] = dot2(t.w, w.w, acc[r]);
            }
        }
        const float bb = l1_b[f];
#pragma unroll
        for (int r = 0; r < 8; ++r) Hh[r * 256 + f] = (_Float16)relu(acc[r] + bb);
    }
    __syncthreads();

    {
        const int c = tid & 127, rh = tid >> 7;
        const unsigned* l2H = wH + OFF_L2 + c * 4;
        const unsigned* HhU = (const unsigned*)Hh;
        float acc[4];
#pragma unroll
        for (int r = 0; r < 4; ++r) acc[r] = 0.f;
        for (int kp4 = 0; kp4 < 32; ++kp4) {
            uint4 w = *(const uint4*)(l2H + kp4 * 512);
#pragma unroll
            for (int r = 0; r < 4; ++r) {
                uint4 t = *(const uint4*)(&HhU[(rh * 4 + r) * 128 + kp4 * 4]);
                acc[r] = dot2(t.x, w.x, acc[r]); acc[r] = dot2(t.y, w.y, acc[r]);
                acc[r] = dot2(t.z, w.z, acc[r]); acc[r] = dot2(t.w, w.w, acc[r]);
            }
        }
        const float lb = l2_b[c];
#pragma unroll
        for (int r = 0; r < 4; ++r) {
            const int rr = rh * 4 + r;
            C[rr * 128 + c] += lb + acc[r];
        }
    }
    __syncthreads();
    ln_rows8_pack(C, CH, n3_g, n3_b, tid);
    __syncthreads();

    {
        const int c = tid & 63, rg = tid >> 6;
        const unsigned* fuH = wH + OFF_FU + c * 4;
        float acc[2];
        const float fb = fu_b[c];
#pragma unroll
        for (int r = 0; r < 2; ++r) acc[r] = fb;
        for (int kp4 = 0; kp4 < 8; ++kp4) {
            uint4 w = *(const uint4*)(fuH + kp4 * 256);
#pragma unroll
            for (int r = 0; r < 2; ++r) {
                uint4 t = *(const uint4*)(&FH[(rg * 2 + r) * 32 + kp4 * 4]);
                acc[r] = dot2(t.x, w.x, acc[r]); acc[r] = dot2(t.y, w.y, acc[r]);
                acc[r] = dot2(t.z, w.z, acc[r]); acc[r] = dot2(t.w, w.w, acc[r]);
            }
        }
        for (int kp4 = 0; kp4 < 16; ++kp4) {
            uint4 w = *(const uint4*)(fuH + (8 + kp4) * 256);
#pragma unroll
            for (int r = 0; r < 2; ++r) {
                uint4 t = *(const uint4*)(&CH[(rg * 2 + r) * 64 + kp4 * 4]);
                acc[r] = dot2(t.x, w.x, acc[r]); acc[r] = dot2(t.y, w.y, acc[r]);
                acc[r] = dot2(t.z, w.z, acc[r]); acc[r] = dot2(t.w, w.w, acc[r]);
            }
        }
#pragma unroll
        for (int r = 0; r < 2; ++r) {
            int row = rg * 2 + r;
            float v = acc[r];
            fused[(r0 + row) * 64 + c] = v;
            A[row * 64 + c] = v;
        }
    }
    __syncthreads();
    if (tid < 64) {
        float s = 0.f, s2 = 0.f;
#pragma unroll
        for (int r = 0; r < 8; ++r) { float x = A[r * 64 + tid]; s += x; s2 += x * x; }
        atomicAdd(&bnSum[tid], s);
        atomicAdd(&bnSq[tid], s2);
    }
}

__global__ __launch_bounds__(256) void k5_bn_cst(
    const float* __restrict__ fused, const float* __restrict__ bnSum,
    const float* __restrict__ bnSq,
    const float* __restrict__ g, const float* __restrict__ b,
    float* __restrict__ out, int N)
{
    const int total = N * 64;
    const float invN = 1.f / (float)N;
    for (int i = blockIdx.x * 256 + threadIdx.x; i < total; i += gridDim.x * 256) {
        int c = i & 63;
        float mu = bnSum[c] * invN;
        float var = bnSq[c] * invN - mu * mu;
        float x = fused[i];
        float y = (x - mu) * rsqrtf(var + 1e-3f) * g[c] + b[c];
        out[i] = relu(y);
    }
}

// ---------------------------------------------------------------------------
extern "C" void kernel_launch(void* const* d_in, const int* in_sizes, int n_in,
                              void* d_out, int out_size, void* d_ws, size_t ws_size,
                              hipStream_t stream)
{
    const int N = in_sizes[0] / 64;   // 8192

    float* src   = (float*)d_ws;                      // N*128 (fallback only)
    float* qs    = src + (size_t)N * 128;             // N*128
    float* ks    = qs + (size_t)N * 128;              // N*128
    float* vs    = ks + (size_t)N * 128;              // N*128
    float* fused = vs + (size_t)N * 128;              // N*64 (fallback only)
    int*   nbr   = (int*)(fused + (size_t)N * 64);    // N*16 ints
    float* bnSum = (float*)(nbr + (size_t)N * 16);    // 64
    float* bnSq  = bnSum + 64;                        // 64 (contiguous 128)
    unsigned* wH = (unsigned*)(bnSq + 64);            // packed weights (~320 KB)

    MegaParams P;
    P.features = (const float*)d_in[0];
    P.coords   = (const int*)d_in[1];
    P.pe_w1 = (const float*)d_in[2];  P.pe_b1 = (const float*)d_in[3];
    P.pe_w2 = (const float*)d_in[4];  P.pe_b2 = (const float*)d_in[5];
    P.in_w  = (const float*)d_in[6];  P.in_b  = (const float*)d_in[7];
    P.q_w   = (const float*)d_in[8];  P.q_b   = (const float*)d_in[9];
    P.k_w   = (const float*)d_in[10]; P.k_b   = (const float*)d_in[11];
    P.v_w   = (const float*)d_in[12]; P.v_b   = (const float*)d_in[13];
    P.o_w   = (const float*)d_in[14]; P.o_b   = (const float*)d_in[15];
    P.n1_g  = (const float*)d_in[16]; P.n1_b  = (const float*)d_in[17];
    P.l1_w  = (const float*)d_in[18]; P.l1_b  = (const float*)d_in[19];
    P.l2_w  = (const float*)d_in[20]; P.l2_b  = (const float*)d_in[21];
    P.n3_g  = (const float*)d_in[22]; P.n3_b  = (const float*)d_in[23];
    P.fu_w  = (const float*)d_in[24]; P.fu_b  = (const float*)d_in[25];
    P.bn_g  = (const float*)d_in[26]; P.bn_b  = (const float*)d_in[27];
    P.qs = qs; P.ks = ks; P.vs = vs; P.nbr = nbr;
    P.bnSum = bnSum; P.bnSq = bnSq; P.wH = wH;
    P.out = (float*)d_out; P.N = N;

    void* args[] = { (void*)&P };
    hipError_t err = hipLaunchCooperativeKernel((const void*)mega_cst,
                                                dim3(N / 16), dim3(256),
                                                args, 0, stream);
    if (err != hipSuccess) {
        // Fallback: proven round-8 4-kernel pipeline.
        k0_pack<<<64, 256, 0, stream>>>(P.q_w, P.k_w, P.v_w, P.o_w,
                                        P.l1_w, P.l2_w, P.in_w, P.pe_w2,
                                        P.fu_w, wH);
        ka_pre_cst<<<N / 8 + N / 16, 256, 0, stream>>>(P.features, P.coords,
                                                       P.pe_w1, P.pe_b1, P.pe_b2,
                                                       P.in_b, wH,
                                                       src, qs, ks, vs, nbr,
                                                       bnSum, N);
        k4_main_cst<<<N / 8, 256, 0, stream>>>(P.features, src, qs, ks, vs, nbr,
                                               P.q_b, P.k_b, P.v_b, wH, P.o_b,
                                               P.n1_g, P.n1_b, P.l1_b, P.l2_b,
                                               P.n3_g, P.n3_b, P.fu_b,
                                               fused, bnSum, bnSq);
        k5_bn_cst<<<512, 256, 0, stream>>>(fused, bnSum, bnSq, P.bn_g, P.bn_b,
                                           (float*)d_out, N);
    }
}

// Round 11
// 209.128 us; speedup vs baseline: 2.6370x; 2.6370x over previous
//
#include <hip/hip_runtime.h>

#define DEVFN __device__ __forceinline__

// NaN-propagating relu (fmaxf(NaN,0)==0 would mask upstream failures).
DEVFN float relu(float x) { return x < 0.f ? 0.f : x; }

// f16 pair helpers: weights/activations packed as half2 in k-major pairs.
// v_dot2_f32_f16: 2 MACs per instr, f32 accumulate.
typedef _Float16 h2 __attribute__((ext_vector_type(2)));
DEVFN float dot2(unsigned a, unsigned b, float c) {
    return __builtin_amdgcn_fdot2(__builtin_bit_cast(h2, a),
                                  __builtin_bit_cast(h2, b), c, false);
}
DEVFN unsigned pack2(float x, float y) {
    h2 h; h.x = (_Float16)x; h.y = (_Float16)y;
    return __builtin_bit_cast(unsigned, h);
}

// Packed-weight layout (round-8 interleaved tile [kp4][c][kp_in], proven):
//   d[kp4*(C*4) + c*4 + (kp&3)] = half2(W[2kp][c], W[2kp+1][c])
// Thread owning col c loads uint4 -> 4 kp pairs, AND lanes c,c+1,... are at
// consecutive 16B addresses -> one coalesced 1KB wave transaction (16 cache
// lines). [Round 6: [kp][c] scalar = 4 lines/instr but 4x instrs (51us).
// Round 7: [c][kp] uint4 = 4x fewer instrs but 64 lines/instr -> 1.5x
// SLOWER. This tile layout = round-6 line traffic + round-7 instr count.]
// Offsets (in dwords) inside the packed-weight workspace region:
#define OFF_Q   0
#define OFF_K   8192
#define OFF_V   16384
#define OFF_O   24576
#define OFF_L1  32768
#define OFF_L2  49152
#define OFF_IN  65536
#define OFF_PE  69632
#define OFF_FU  73728
#define PACKED_TOTAL 79872

// ---------------------------------------------------------------------------
// K0: pack all weight matrices to half2 tiles (runs once before ka).
// ---------------------------------------------------------------------------
__global__ __launch_bounds__(256) void k0_pack(
    const float* __restrict__ q_w, const float* __restrict__ k_w,
    const float* __restrict__ v_w, const float* __restrict__ o_w,
    const float* __restrict__ l1_w, const float* __restrict__ l2_w,
    const float* __restrict__ in_w, const float* __restrict__ pe_w2,
    const float* __restrict__ fu_w, unsigned* __restrict__ dst)
{
    const int gid = blockIdx.x * 256 + threadIdx.x;
    const int stride = gridDim.x * 256;
    auto packmat = [&](const float* s, int K, int C, unsigned* d) {
        const int kp2 = K / 2;        // always divisible by 4 here
        const int n = kp2 * C;
        const int c4 = C * 4;
        for (int i = gid; i < n; i += stride) {
            int kp4 = i / c4;
            int rem = i - kp4 * c4;
            int c = rem >> 2, ki = rem & 3;
            int kp = kp4 * 4 + ki;
            d[i] = pack2(s[(2 * kp) * C + c], s[(2 * kp + 1) * C + c]);
        }
    };
    packmat(q_w, 128, 128, dst + OFF_Q);
    packmat(k_w, 128, 128, dst + OFF_K);
    packmat(v_w, 128, 128, dst + OFF_V);
    packmat(o_w, 128, 128, dst + OFF_O);
    packmat(l1_w, 128, 256, dst + OFF_L1);
    packmat(l2_w, 256, 128, dst + OFF_L2);
    packmat(in_w, 64, 128, dst + OFF_IN);
    packmat(pe_w2, 64, 128, dst + OFF_PE);
    packmat(fu_w, 192, 64, dst + OFF_FU);
}

// ---------------------------------------------------------------------------
// KA: fused pre-work, two block roles interleaved (bx%3): 2/3 src, 1/3 nbr.
//  src role : src = features@in_w+in_b + relu(pe)@pe_w2+pe_b2 ; qs/ks/vs
//  nbr role : neighbor top-16 (manhattan<=4, stable); nbr-block 0 zeros BN.
// Round-6 structure; weight streams = coalesced uint4 tile loads.
// [Round 9/10 lesson: cooperative mega-fusion of the pipeline is 4x slower
//  (grid.sync serialization at 2 blocks/CU); the dur_us vs sum-of-kernels
//  gap (~100-140us) is fixed harness overhead, NOT per-launch cost.]
// ---------------------------------------------------------------------------
__global__ __launch_bounds__(256, 4) void ka_pre_cst(
    const float* __restrict__ features, const int* __restrict__ coords,
    const float* __restrict__ pe_w1, const float* __restrict__ pe_b1,
    const float* __restrict__ pe_b2,
    const float* __restrict__ in_b,
    const unsigned* __restrict__ wH,          // packed weights
    float* __restrict__ src,
    float* __restrict__ qs, float* __restrict__ ks, float* __restrict__ vs,
    int* __restrict__ nbr, float* __restrict__ bnAcc, int N)
{
    // src-role LDS
    __shared__ __align__(16) float S[1024];       // 8 x 128 src f32
    __shared__ __align__(16) unsigned SH[512];    // 8 x 64 src packed
    __shared__ __align__(16) unsigned FHp[256];   // 8 x 32 features packed
    __shared__ __align__(16) unsigned HHp[256];   // 8 x 32 pe-hidden packed
    __shared__ int   sC[24];
    // nbr-role LDS
    __shared__ int cnt[16];
    __shared__ int lst[16 * 64];
    __shared__ int outL[256];

    const int tid = threadIdx.x;
    const int bx = blockIdx.x;
    const int role_nbr = (bx % 3) == 2;

    if (role_nbr) {
        // ---------------- nbr role: neighbor search -----------------------
        const int nb = bx / 3;
        const int q0 = nb * 16;
        if (nb == 0 && tid < 128) bnAcc[tid] = 0.f;
        if (tid < 16) cnt[tid] = 0;
        outL[tid] = -1;
        __syncthreads();
        int qx[16], qy[16], qz[16];
#pragma unroll
        for (int q = 0; q < 16; ++q) {
            qx[q] = coords[(q0 + q) * 3 + 0];
            qy[q] = coords[(q0 + q) * 3 + 1];
            qz[q] = coords[(q0 + q) * 3 + 2];
        }
        for (int cd = tid; cd < N; cd += 256) {
            int cx = coords[cd * 3 + 0];
            int cy = coords[cd * 3 + 1];
            int cz = coords[cd * 3 + 2];
#pragma unroll
            for (int q = 0; q < 16; ++q) {
                int dx = cx - qx[q]; dx = dx < 0 ? -dx : dx;
                int dy = cy - qy[q]; dy = dy < 0 ? -dy : dy;
                int dz = cz - qz[q]; dz = dz < 0 ? -dz : dz;
                int d = dx + dy + dz;
                if (d <= 4) {
                    int s = atomicAdd(&cnt[q], 1);
                    if (s < 64) lst[q * 64 + s] = (d << 13) | cd;
                }
            }
        }
        __syncthreads();
        {
            const int q = tid >> 4, t = tid & 15;
            int n = cnt[q]; if (n > 64) n = 64;
            for (int e = t; e < n; e += 16) {
                int key = lst[q * 64 + e];
                int rank = 0;
                for (int j = 0; j < n; ++j) rank += (lst[q * 64 + j] < key) ? 1 : 0;
                if (rank < 16) outL[q * 16 + rank] = key & 8191;
            }
        }
        __syncthreads();
        {
            const int q = tid >> 4, t = tid & 15;
            nbr[(q0 + q) * 16 + t] = outL[q * 16 + t];
        }
        return;
    }

    // ---------------- src role: src + q/k/v projections -------------------
    const int sb = (bx / 3) * 2 + (bx % 3);   // 0..1023
    const int r0 = sb * 8;
    if (tid < 24) sC[tid] = coords[r0 * 3 + tid];
    if (tid < 256) {   // features 8x64 -> packed pairs
        float2 f = *(const float2*)(features + r0 * 64 + tid * 2);
        FHp[tid] = pack2(f.x, f.y);
    }
    __syncthreads();
    if (tid < 256) {   // pe hidden, 2 cols per thread, packed
        int r = tid >> 5, t2 = (tid & 31) * 2;
        float v0 = sC[r * 3 + 0] * (1.f / 95.f);
        float v1 = sC[r * 3 + 1] * (1.f / 95.f);
        float v2 = sC[r * 3 + 2] * (1.f / 95.f);
        float h0 = v0 * pe_w1[t2] + v1 * pe_w1[64 + t2] + v2 * pe_w1[128 + t2] + pe_b1[t2];
        float h1 = v0 * pe_w1[t2 + 1] + v1 * pe_w1[64 + t2 + 1] + v2 * pe_w1[128 + t2 + 1] + pe_b1[t2 + 1];
        HHp[tid] = pack2(relu(h0), relu(h1));
    }
    __syncthreads();
    const int c = tid & 127, rh = tid >> 7;
    {
        // src = F@in_w + H@pe_w2 + (in_b + pe_b2); tile uint4 weights
        const unsigned* inH = wH + OFF_IN + c * 4;   // + kp4*512
        const unsigned* peH = wH + OFF_PE + c * 4;
        float acc[4];
        const float base = in_b[c] + pe_b2[c];
#pragma unroll
        for (int r = 0; r < 4; ++r) acc[r] = base;
        for (int kp4 = 0; kp4 < 8; ++kp4) {
            uint4 wi = *(const uint4*)(inH + kp4 * 512);
            uint4 wp = *(const uint4*)(peH + kp4 * 512);
#pragma unroll
            for (int r = 0; r < 4; ++r) {
                const int rr = rh * 4 + r;
                uint4 f = *(const uint4*)(&FHp[rr * 32 + kp4 * 4]);
                uint4 h = *(const uint4*)(&HHp[rr * 32 + kp4 * 4]);
                acc[r] = dot2(f.x, wi.x, acc[r]); acc[r] = dot2(f.y, wi.y, acc[r]);
                acc[r] = dot2(f.z, wi.z, acc[r]); acc[r] = dot2(f.w, wi.w, acc[r]);
                acc[r] = dot2(h.x, wp.x, acc[r]); acc[r] = dot2(h.y, wp.y, acc[r]);
                acc[r] = dot2(h.z, wp.z, acc[r]); acc[r] = dot2(h.w, wp.w, acc[r]);
            }
        }
#pragma unroll
        for (int r = 0; r < 4; ++r) {
            src[(r0 + rh * 4 + r) * 128 + c] = acc[r];
            S[(rh * 4 + r) * 128 + c] = acc[r];
        }
    }
    __syncthreads();
    // pack S -> SH (pairs along the col axis, which is K for q/k/v)
    for (int i = tid; i < 512; i += 256) {
        float2 s = *(const float2*)(&S[i * 2]);
        SH[i] = pack2(s.x, s.y);
    }
    __syncthreads();
    // q/k/v in one pass: 3 coalesced uint4 tile streams, dot2
    {
        const unsigned* qH = wH + OFF_Q + c * 4;   // + kp4*512
        const unsigned* kH = wH + OFF_K + c * 4;
        const unsigned* vH = wH + OFF_V + c * 4;
        float aq[4], ak[4], av[4];
#pragma unroll
        for (int r = 0; r < 4; ++r) { aq[r] = 0.f; ak[r] = 0.f; av[r] = 0.f; }
        for (int kp4 = 0; kp4 < 16; ++kp4) {
            uint4 wq = *(const uint4*)(qH + kp4 * 512);
            uint4 wk = *(const uint4*)(kH + kp4 * 512);
            uint4 wv = *(const uint4*)(vH + kp4 * 512);
#pragma unroll
            for (int r = 0; r < 4; ++r) {
                uint4 s4 = *(const uint4*)(&SH[(rh * 4 + r) * 64 + kp4 * 4]);
                aq[r] = dot2(s4.x, wq.x, aq[r]); aq[r] = dot2(s4.y, wq.y, aq[r]);
                aq[r] = dot2(s4.z, wq.z, aq[r]); aq[r] = dot2(s4.w, wq.w, aq[r]);
                ak[r] = dot2(s4.x, wk.x, ak[r]); ak[r] = dot2(s4.y, wk.y, ak[r]);
                ak[r] = dot2(s4.z, wk.z, ak[r]); ak[r] = dot2(s4.w, wk.w, ak[r]);
                av[r] = dot2(s4.x, wv.x, av[r]); av[r] = dot2(s4.y, wv.y, av[r]);
                av[r] = dot2(s4.z, wv.z, av[r]); av[r] = dot2(s4.w, wv.w, av[r]);
            }
        }
#pragma unroll
        for (int r = 0; r < 4; ++r) {
            qs[(r0 + rh * 4 + r) * 128 + c] = aq[r];
            ks[(r0 + rh * 4 + r) * 128 + c] = ak[r];
            vs[(r0 + rh * 4 + r) * 128 + c] = av[r];
        }
    }
}

// ---------------------------------------------------------------------------
// K4: attention + o-proj + LN1 + FFN + LN2 + fusion + BN partials.
// Round-6 structure; weight streams = coalesced uint4 tile loads.
// ---------------------------------------------------------------------------
DEVFN void ln_rows8_pack(float* Cb, unsigned* CHp, const float* __restrict__ g,
                         const float* __restrict__ b, int tid)
{
    const int r = tid >> 5, l = tid & 31;
    float x[4]; float s = 0.f, s2 = 0.f;
#pragma unroll
    for (int i = 0; i < 4; ++i) {
        x[i] = Cb[r * 128 + l * 4 + i];
        s += x[i]; s2 += x[i] * x[i];
    }
#pragma unroll
    for (int o = 1; o < 32; o <<= 1) { s += __shfl_xor(s, o); s2 += __shfl_xor(s2, o); }
    float mu = s * (1.f / 128.f);
    float var = s2 * (1.f / 128.f) - mu * mu;
    float rstd = rsqrtf(var + 1e-5f);
    float y[4];
#pragma unroll
    for (int i = 0; i < 4; ++i) {
        int cc = l * 4 + i;
        y[i] = (x[i] - mu) * rstd * g[cc] + b[cc];
        Cb[r * 128 + cc] = y[i];
    }
    CHp[r * 64 + l * 2]     = pack2(y[0], y[1]);
    CHp[r * 64 + l * 2 + 1] = pack2(y[2], y[3]);
}

__global__ __launch_bounds__(256, 4) void k4_main_cst(
    const float* __restrict__ features, const float* __restrict__ src,
    const float* __restrict__ qs, const float* __restrict__ ks, const float* __restrict__ vs,
    const int* __restrict__ nbr,
    const float* __restrict__ q_b, const float* __restrict__ k_b,
    const float* __restrict__ v_b,
    const unsigned* __restrict__ wH,
    const float* __restrict__ o_b,
    const float* __restrict__ n1_g, const float* __restrict__ n1_b,
    const float* __restrict__ l1_b,
    const float* __restrict__ l2_b,
    const float* __restrict__ n3_g, const float* __restrict__ n3_b,
    const float* __restrict__ fu_b,
    float* __restrict__ fused, float* __restrict__ bnSum, float* __restrict__ bnSq)
{
    __shared__ __align__(16) float A[1024];        // src tile; P5 BN staging
    __shared__ __align__(16) float C[1024];        // running activation f32
    __shared__ __align__(16) float Q[1024];        // q rows (bias applied)
    __shared__ __align__(16) float SC[512];        // attention scores
    __shared__ __align__(16) unsigned BtH[512];    // head_out packed 8x64
    __shared__ __align__(16) unsigned CH[512];     // tgt packed 8x64
    __shared__ __align__(16) unsigned FH[256];     // features packed 8x32
    __shared__ __align__(16) _Float16 Hh[2048];    // ffn hidden f16 8x256
    __shared__ __align__(16) float bK[128], bV[128];
    __shared__ int idxL[128];
    const int tid = threadIdx.x;
    const int r0 = blockIdx.x * 8;

    for (int i = tid; i < 1024; i += 256) A[i] = src[r0 * 128 + i];
    if (tid < 256) {
        float2 f = *(const float2*)(features + r0 * 64 + tid * 2);
        FH[tid] = pack2(f.x, f.y);
    }
    if (tid < 128) {
        idxL[tid] = nbr[r0 * 16 + tid];
        bK[tid] = k_b[tid]; bV[tid] = v_b[tid];
    }
    __syncthreads();
    {   // vectorized Q gather + bias: thread = (row=tid>>5, colgroup=tid&31)
        int r = tid >> 5, cg = tid & 31;
        int i0 = idxL[r * 16];
        float4 qv = make_float4(0.f, 0.f, 0.f, 0.f);
        if (i0 >= 0) qv = *(const float4*)(qs + i0 * 128 + cg * 4);
        float4 qb = *(const float4*)(q_b + cg * 4);
        qv.x += qb.x; qv.y += qb.y; qv.z += qb.z; qv.w += qb.w;
        *(float4*)(&Q[r * 128 + cg * 4]) = qv;
    }
    __syncthreads();

    // ---- phase 1a: scores. thread = (row r, head h, group g of 8) --------
    // s_j = q.(k_j + kb) = q.k_j + q.kb ; q.kb hoisted (same ch for both j).
    const int ar = tid >> 5, ah = (tid >> 3) & 3, ag = tid & 7;
    {
        const int ch = ag & 3;
        float sbias = 0.f;
#pragma unroll
        for (int c4 = 0; c4 < 8; ++c4) {
            float4 qv = *(const float4*)(&Q[ar * 128 + ah * 32 + c4 * 4]);
            float4 kb = *(const float4*)(&bK[ch * 32 + c4 * 4]);
            sbias += qv.x * kb.x + qv.y * kb.y + qv.z * kb.z + qv.w * kb.w;
        }
#pragma unroll
        for (int jj = 0; jj < 2; ++jj) {
            int j = ag + jj * 8;
            int j4 = j >> 2;
            int id = idxL[ar * 16 + ah * 4 + j4];
            float s = 0.f;
            if (id >= 0) {
#pragma unroll
                for (int c4 = 0; c4 < 8; ++c4) {
                    float4 qv = *(const float4*)(&Q[ar * 128 + ah * 32 + c4 * 4]);
                    float4 kv = *(const float4*)(ks + id * 128 + ch * 32 + c4 * 4);
                    s += qv.x * kv.x + qv.y * kv.y + qv.z * kv.z + qv.w * kv.w;
                }
            }
            SC[ar * 64 + ah * 16 + j] = (s + sbias) * 0.08838834764831845f;
        }
    }
    __syncthreads();

    // ---- phase 1b: softmax + P@V (sum w = 1 => +vb once); packed write ---
    {
        float p[16];
        float mx = -3.4e38f;
#pragma unroll
        for (int j = 0; j < 16; ++j) { p[j] = SC[ar * 64 + ah * 16 + j]; mx = fmaxf(mx, p[j]); }
        float sum = 0.f;
#pragma unroll
        for (int j = 0; j < 16; ++j) { p[j] = __expf(p[j] - mx); sum += p[j]; }
        float inv = 1.f / sum;
        float4 acc = make_float4(0.f, 0.f, 0.f, 0.f);
#pragma unroll
        for (int j = 0; j < 16; ++j) {
            int j4 = j >> 2, ch = j & 3;
            int id = idxL[ar * 16 + ah * 4 + j4];
            float w = p[j] * inv;
            if (id >= 0) {
                float4 vv = *(const float4*)(vs + id * 128 + ch * 32 + ag * 4);
                acc.x += w * vv.x; acc.y += w * vv.y;
                acc.z += w * vv.z; acc.w += w * vv.w;
            }
        }
        float4 vb = *(const float4*)(&bV[ah * 32 + ag * 4]);
        acc.x += vb.x; acc.y += vb.y; acc.z += vb.z; acc.w += vb.w;
        BtH[ar * 64 + ah * 16 + ag * 2]     = pack2(acc.x, acc.y);
        BtH[ar * 64 + ah * 16 + ag * 2 + 1] = pack2(acc.z, acc.w);
    }
    __syncthreads();

    // ---- phase 2: C = A + head_out @ o_w + o_b (tile uint4 w) ------------
    {
        const int c = tid & 127, rh = tid >> 7;
        const unsigned* oH = wH + OFF_O + c * 4;   // + kp4*512
        float acc[4];
#pragma unroll
        for (int r = 0; r < 4; ++r) acc[r] = 0.f;
        for (int kp4 = 0; kp4 < 16; ++kp4) {
            uint4 w = *(const uint4*)(oH + kp4 * 512);
#pragma unroll
            for (int r = 0; r < 4; ++r) {
                uint4 t = *(const uint4*)(&BtH[(rh * 4 + r) * 64 + kp4 * 4]);
                acc[r] = dot2(t.x, w.x, acc[r]); acc[r] = dot2(t.y, w.y, acc[r]);
                acc[r] = dot2(t.z, w.z, acc[r]); acc[r] = dot2(t.w, w.w, acc[r]);
            }
        }
        const float ob = o_b[c];
#pragma unroll
        for (int r = 0; r < 4; ++r) {
            const int rr = rh * 4 + r;
            C[rr * 128 + c] = A[rr * 128 + c] + ob + acc[r];
        }
    }
    __syncthreads();
    ln_rows8_pack(C, CH, n1_g, n1_b, tid);   // C = tgt (f32 + packed)
    __syncthreads();

    // ---- phase 3: Hh = relu(CH @ l1_w + l1_b)  [8 x 256] f16 out ---------
    {
        const int f = tid;
        const unsigned* l1H = wH + OFF_L1 + f * 4;   // + kp4*1024 (C=256)
        float acc[8];
#pragma unroll
        for (int r = 0; r < 8; ++r) acc[r] = 0.f;
        for (int kp4 = 0; kp4 < 16; ++kp4) {
            uint4 w = *(const uint4*)(l1H + kp4 * 1024);
#pragma unroll
            for (int r = 0; r < 8; ++r) {
                uint4 t = *(const uint4*)(&CH[r * 64 + kp4 * 4]);
                acc[r] = dot2(t.x, w.x, acc[r]); acc[r] = dot2(t.y, w.y, acc[r]);
                acc[r] = dot2(t.z, w.z, acc[r]); acc[r] = dot2(t.w, w.w, acc[r]);
            }
        }
        const float bb = l1_b[f];
#pragma unroll
        for (int r = 0; r < 8; ++r) Hh[r * 256 + f] = (_Float16)relu(acc[r] + bb);
    }
    __syncthreads();

    // ---- phase 4: C += Hh @ l2_w + l2_b (K=256, tile uint4 w) ------------
    {
        const int c = tid & 127, rh = tid >> 7;
        const unsigned* l2H = wH + OFF_L2 + c * 4;   // + kp4*512, kp4 0..31
        const unsigned* HhU = (const unsigned*)Hh;   // 8 x 128 dwords
        float acc[4];
#pragma unroll
        for (int r = 0; r < 4; ++r) acc[r] = 0.f;
        for (int kp4 = 0; kp4 < 32; ++kp4) {
            uint4 w = *(const uint4*)(l2H + kp4 * 512);
#pragma unroll
            for (int r = 0; r < 4; ++r) {
                uint4 t = *(const uint4*)(&HhU[(rh * 4 + r) * 128 + kp4 * 4]);
                acc[r] = dot2(t.x, w.x, acc[r]); acc[r] = dot2(t.y, w.y, acc[r]);
                acc[r] = dot2(t.z, w.z, acc[r]); acc[r] = dot2(t.w, w.w, acc[r]);
            }
        }
        const float lb = l2_b[c];
#pragma unroll
        for (int r = 0; r < 4; ++r) {
            const int rr = rh * 4 + r;
            C[rr * 128 + c] += lb + acc[r];
        }
    }
    __syncthreads();
    ln_rows8_pack(C, CH, n3_g, n3_b, tid);   // C = final tgt (f32 + packed)
    __syncthreads();

    // ---- phase 5: fused = [F, C] @ fu_w + fu_b; BN staging in A ----------
    {
        const int c = tid & 63, rg = tid >> 6;   // 4 groups x 2 rows
        const unsigned* fuH = wH + OFF_FU + c * 4;   // + kp4*256 (C=64)
        float acc[2];
        const float fb = fu_b[c];
#pragma unroll
        for (int r = 0; r < 2; ++r) acc[r] = fb;
        for (int kp4 = 0; kp4 < 8; ++kp4) {      // features half: kp4 0..7
            uint4 w = *(const uint4*)(fuH + kp4 * 256);
#pragma unroll
            for (int r = 0; r < 2; ++r) {
                uint4 t = *(const uint4*)(&FH[(rg * 2 + r) * 32 + kp4 * 4]);
                acc[r] = dot2(t.x, w.x, acc[r]); acc[r] = dot2(t.y, w.y, acc[r]);
                acc[r] = dot2(t.z, w.z, acc[r]); acc[r] = dot2(t.w, w.w, acc[r]);
            }
        }
        for (int kp4 = 0; kp4 < 16; ++kp4) {     // tgt half: kp4 8..23
            uint4 w = *(const uint4*)(fuH + (8 + kp4) * 256);
#pragma unroll
            for (int r = 0; r < 2; ++r) {
                uint4 t = *(const uint4*)(&CH[(rg * 2 + r) * 64 + kp4 * 4]);
                acc[r] = dot2(t.x, w.x, acc[r]); acc[r] = dot2(t.y, w.y, acc[r]);
                acc[r] = dot2(t.z, w.z, acc[r]); acc[r] = dot2(t.w, w.w, acc[r]);
            }
        }
#pragma unroll
        for (int r = 0; r < 2; ++r) {
            int row = rg * 2 + r;
            float v = acc[r];
            fused[(r0 + row) * 64 + c] = v;
            A[row * 64 + c] = v;
        }
    }
    __syncthreads();
    if (tid < 64) {
        float s = 0.f, s2 = 0.f;
#pragma unroll
        for (int r = 0; r < 8; ++r) { float x = A[r * 64 + tid]; s += x; s2 += x * x; }
        atomicAdd(&bnSum[tid], s);
        atomicAdd(&bnSq[tid], s2);
    }
}

// ---------------------------------------------------------------------------
// K5: batchnorm (train-mode stats) + relu -> fp32 out
// ---------------------------------------------------------------------------
__global__ __launch_bounds__(256) void k5_bn_cst(
    const float* __restrict__ fused, const float* __restrict__ bnSum,
    const float* __restrict__ bnSq,
    const float* __restrict__ g, const float* __restrict__ b,
    float* __restrict__ out, int N)
{
    const int total = N * 64;
    const float invN = 1.f / (float)N;
    for (int i = blockIdx.x * 256 + threadIdx.x; i < total; i += gridDim.x * 256) {
        int c = i & 63;
        float mu = bnSum[c] * invN;
        float var = bnSq[c] * invN - mu * mu;
        float x = fused[i];
        float y = (x - mu) * rsqrtf(var + 1e-3f) * g[c] + b[c];
        out[i] = relu(y);
    }
}

// ---------------------------------------------------------------------------
extern "C" void kernel_launch(void* const* d_in, const int* in_sizes, int n_in,
                              void* d_out, int out_size, void* d_ws, size_t ws_size,
                              hipStream_t stream)
{
    const float* features = (const float*)d_in[0];
    const int*   coords   = (const int*)d_in[1];
    const float* pe_w1 = (const float*)d_in[2];
    const float* pe_b1 = (const float*)d_in[3];
    const float* pe_w2 = (const float*)d_in[4];
    const float* pe_b2 = (const float*)d_in[5];
    const float* in_w  = (const float*)d_in[6];
    const float* in_b  = (const float*)d_in[7];
    const float* q_w   = (const float*)d_in[8];
    const float* q_b   = (const float*)d_in[9];
    const float* k_w   = (const float*)d_in[10];
    const float* k_b   = (const float*)d_in[11];
    const float* v_w   = (const float*)d_in[12];
    const float* v_b   = (const float*)d_in[13];
    const float* o_w   = (const float*)d_in[14];
    const float* o_b   = (const float*)d_in[15];
    const float* n1_g  = (const float*)d_in[16];
    const float* n1_b  = (const float*)d_in[17];
    const float* l1_w  = (const float*)d_in[18];
    const float* l1_b  = (const float*)d_in[19];
    const float* l2_w  = (const float*)d_in[20];
    const float* l2_b  = (const float*)d_in[21];
    const float* n3_g  = (const float*)d_in[22];
    const float* n3_b  = (const float*)d_in[23];
    const float* fu_w  = (const float*)d_in[24];
    const float* fu_b  = (const float*)d_in[25];
    const float* bn_g  = (const float*)d_in[26];
    const float* bn_b  = (const float*)d_in[27];

    const int N = in_sizes[0] / 64;   // 8192

    float* src   = (float*)d_ws;            // N*128
    float* qs    = src + (size_t)N * 128;   // N*128
    float* ks    = qs  + (size_t)N * 128;   // N*128
    float* vs    = ks  + (size_t)N * 128;   // N*128
    float* fused = vs  + (size_t)N * 128;   // N*64
    int*   nbr    = (int*)(fused + (size_t)N * 64);   // N*16 ints
    float* bnSum  = (float*)(nbr + (size_t)N * 16);   // 64
    float* bnSq   = bnSum + 64;                       // 64 (contiguous 128)
    unsigned* wH  = (unsigned*)(bnSq + 64);           // packed weights (~320 KB)

    k0_pack<<<64, 256, 0, stream>>>(q_w, k_w, v_w, o_w, l1_w, l2_w,
                                    in_w, pe_w2, fu_w, wH);
    ka_pre_cst<<<N / 8 + N / 16, 256, 0, stream>>>(features, coords,
                                                   pe_w1, pe_b1, pe_b2, in_b,
                                                   wH,
                                                   src, qs, ks, vs, nbr, bnSum, N);
    k4_main_cst<<<N / 8, 256, 0, stream>>>(features, src, qs, ks, vs, nbr,
                                           q_b, k_b, v_b, wH, o_b, n1_g, n1_b,
                                           l1_b, l2_b, n3_g, n3_b,
                                           fu_b, fused, bnSum, bnSq);
    k5_bn_cst<<<512, 256, 0, stream>>>(fused, bnSum, bnSq, bn_g, bn_b,
                                       (float*)d_out, N);
}

// Round 12
// 196.582 us; speedup vs baseline: 2.8053x; 1.0638x over previous
//
#include <hip/hip_runtime.h>

#define DEVFN __device__ __forceinline__

// NaN-propagating relu (fmaxf(NaN,0)==0 would mask upstream failures).
DEVFN float relu(float x) { return x < 0.f ? 0.f : x; }

// f16 pair helpers: weights/activations packed as half2 in k-major pairs.
// v_dot2_f32_f16: 2 MACs per instr, f32 accumulate.
typedef _Float16 h2 __attribute__((ext_vector_type(2)));
DEVFN float dot2(unsigned a, unsigned b, float c) {
    return __builtin_amdgcn_fdot2(__builtin_bit_cast(h2, a),
                                  __builtin_bit_cast(h2, b), c, false);
}
DEVFN unsigned pack2(float x, float y) {
    h2 h; h.x = (_Float16)x; h.y = (_Float16)y;
    return __builtin_bit_cast(unsigned, h);
}

// Manhattan distance of byte-packed coords (x|y<<8|z<<16): one v_sad_u8.
// Byte 3 is zero in both operands -> contributes 0.
DEVFN unsigned sad3(unsigned a, unsigned b) {
#if __has_builtin(__builtin_amdgcn_sad_u8)
    return __builtin_amdgcn_sad_u8(a, b, 0u);
#else
    int dx = (int)(a & 255u) - (int)(b & 255u); dx = dx < 0 ? -dx : dx;
    int dy = (int)((a >> 8) & 255u) - (int)((b >> 8) & 255u); dy = dy < 0 ? -dy : dy;
    int dz = (int)((a >> 16) & 255u) - (int)((b >> 16) & 255u); dz = dz < 0 ? -dz : dz;
    return (unsigned)(dx + dy + dz);
#endif
}

// Packed-weight layout (round-8 interleaved tile [kp4][c][kp_in], proven):
//   d[kp4*(C*4) + c*4 + (kp&3)] = half2(W[2kp][c], W[2kp+1][c])
// Thread owning col c loads uint4 -> 4 kp pairs, AND lanes c,c+1,... are at
// consecutive 16B addresses -> one coalesced 1KB wave transaction (16 cache
// lines). [Round 6: [kp][c] scalar = 4 lines/instr but 4x instrs (51us).
// Round 7: [c][kp] uint4 = 4x fewer instrs but 64 lines/instr -> 1.5x
// SLOWER. This tile layout = round-6 line traffic + round-7 instr count.]
// Offsets (in dwords) inside the packed-weight workspace region:
#define OFF_Q   0
#define OFF_K   8192
#define OFF_V   16384
#define OFF_O   24576
#define OFF_L1  32768
#define OFF_L2  49152
#define OFF_IN  65536
#define OFF_PE  69632
#define OFF_FU  73728
#define PACKED_TOTAL 79872

// ---------------------------------------------------------------------------
// K0: pack all weight matrices to half2 tiles + coords to bytes (runs once).
// ---------------------------------------------------------------------------
__global__ __launch_bounds__(256) void k0_pack(
    const float* __restrict__ q_w, const float* __restrict__ k_w,
    const float* __restrict__ v_w, const float* __restrict__ o_w,
    const float* __restrict__ l1_w, const float* __restrict__ l2_w,
    const float* __restrict__ in_w, const float* __restrict__ pe_w2,
    const float* __restrict__ fu_w, const int* __restrict__ coords,
    unsigned* __restrict__ dst, unsigned* __restrict__ pcoords, int N)
{
    const int gid = blockIdx.x * 256 + threadIdx.x;
    const int stride = gridDim.x * 256;
    auto packmat = [&](const float* s, int K, int C, unsigned* d) {
        const int kp2 = K / 2;        // always divisible by 4 here
        const int n = kp2 * C;
        const int c4 = C * 4;
        for (int i = gid; i < n; i += stride) {
            int kp4 = i / c4;
            int rem = i - kp4 * c4;
            int c = rem >> 2, ki = rem & 3;
            int kp = kp4 * 4 + ki;
            d[i] = pack2(s[(2 * kp) * C + c], s[(2 * kp + 1) * C + c]);
        }
    };
    packmat(q_w, 128, 128, dst + OFF_Q);
    packmat(k_w, 128, 128, dst + OFF_K);
    packmat(v_w, 128, 128, dst + OFF_V);
    packmat(o_w, 128, 128, dst + OFF_O);
    packmat(l1_w, 128, 256, dst + OFF_L1);
    packmat(l2_w, 256, 128, dst + OFF_L2);
    packmat(in_w, 64, 128, dst + OFF_IN);
    packmat(pe_w2, 64, 128, dst + OFF_PE);
    packmat(fu_w, 192, 64, dst + OFF_FU);
    for (int i = gid; i < N; i += stride) {
        unsigned x = (unsigned)coords[i * 3 + 0];
        unsigned y = (unsigned)coords[i * 3 + 1];
        unsigned z = (unsigned)coords[i * 3 + 2];
        pcoords[i] = x | (y << 8) | (z << 16);
    }
}

// ---------------------------------------------------------------------------
// KA: fused pre-work, two block roles interleaved (bx%3): 2/3 src, 1/3 nbr.
//  src role : src = features@in_w+in_b + relu(pe)@pe_w2+pe_b2 ; qs/ks/vs
//  nbr role : neighbor top-16 (manhattan<=4, stable); nbr-block 0 zeros BN.
// nbr scan uses byte-packed coords + v_sad_u8: 1 load + ~2 VALU per
// (candidate, query) vs 3 loads + ~9 VALU (scan was ~27us of ka's 50us).
// ---------------------------------------------------------------------------
__global__ __launch_bounds__(256, 4) void ka_pre_cst(
    const float* __restrict__ features, const int* __restrict__ coords,
    const unsigned* __restrict__ pcoords,
    const float* __restrict__ pe_w1, const float* __restrict__ pe_b1,
    const float* __restrict__ pe_b2,
    const float* __restrict__ in_b,
    const unsigned* __restrict__ wH,          // packed weights
    float* __restrict__ src,
    float* __restrict__ qs, float* __restrict__ ks, float* __restrict__ vs,
    int* __restrict__ nbr, float* __restrict__ bnAcc, int N)
{
    // src-role LDS
    __shared__ __align__(16) float S[1024];       // 8 x 128 src f32
    __shared__ __align__(16) unsigned SH[512];    // 8 x 64 src packed
    __shared__ __align__(16) unsigned FHp[256];   // 8 x 32 features packed
    __shared__ __align__(16) unsigned HHp[256];   // 8 x 32 pe-hidden packed
    __shared__ int   sC[24];
    // nbr-role LDS
    __shared__ int cnt[16];
    __shared__ int lst[16 * 64];
    __shared__ int outL[256];

    const int tid = threadIdx.x;
    const int bx = blockIdx.x;
    const int role_nbr = (bx % 3) == 2;

    if (role_nbr) {
        // ---------------- nbr role: neighbor search -----------------------
        const int nb = bx / 3;
        const int q0 = nb * 16;
        if (nb == 0 && tid < 128) bnAcc[tid] = 0.f;
        if (tid < 16) cnt[tid] = 0;
        outL[tid] = -1;
        __syncthreads();
        unsigned pq[16];
#pragma unroll
        for (int q = 0; q < 16; ++q) pq[q] = pcoords[q0 + q];
        for (int cd = tid; cd < N; cd += 256) {
            unsigned pcv = pcoords[cd];
#pragma unroll
            for (int q = 0; q < 16; ++q) {
                unsigned d = sad3(pcv, pq[q]);
                if (d <= 4u) {
                    int s = atomicAdd(&cnt[q], 1);
                    if (s < 64) lst[q * 64 + s] = ((int)d << 13) | cd;
                }
            }
        }
        __syncthreads();
        {
            const int q = tid >> 4, t = tid & 15;
            int n = cnt[q]; if (n > 64) n = 64;
            for (int e = t; e < n; e += 16) {
                int key = lst[q * 64 + e];
                int rank = 0;
                for (int j = 0; j < n; ++j) rank += (lst[q * 64 + j] < key) ? 1 : 0;
                if (rank < 16) outL[q * 16 + rank] = key & 8191;
            }
        }
        __syncthreads();
        {
            const int q = tid >> 4, t = tid & 15;
            nbr[(q0 + q) * 16 + t] = outL[q * 16 + t];
        }
        return;
    }

    // ---------------- src role: src + q/k/v projections -------------------
    const int sb = (bx / 3) * 2 + (bx % 3);   // 0..1023
    const int r0 = sb * 8;
    if (tid < 24) sC[tid] = coords[r0 * 3 + tid];
    if (tid < 256) {   // features 8x64 -> packed pairs
        float2 f = *(const float2*)(features + r0 * 64 + tid * 2);
        FHp[tid] = pack2(f.x, f.y);
    }
    __syncthreads();
    if (tid < 256) {   // pe hidden, 2 cols per thread, packed
        int r = tid >> 5, t2 = (tid & 31) * 2;
        float v0 = sC[r * 3 + 0] * (1.f / 95.f);
        float v1 = sC[r * 3 + 1] * (1.f / 95.f);
        float v2 = sC[r * 3 + 2] * (1.f / 95.f);
        float h0 = v0 * pe_w1[t2] + v1 * pe_w1[64 + t2] + v2 * pe_w1[128 + t2] + pe_b1[t2];
        float h1 = v0 * pe_w1[t2 + 1] + v1 * pe_w1[64 + t2 + 1] + v2 * pe_w1[128 + t2 + 1] + pe_b1[t2 + 1];
        HHp[tid] = pack2(relu(h0), relu(h1));
    }
    __syncthreads();
    const int c = tid & 127, rh = tid >> 7;
    {
        // src = F@in_w + H@pe_w2 + (in_b + pe_b2); tile uint4 weights
        const unsigned* inH = wH + OFF_IN + c * 4;   // + kp4*512
        const unsigned* peH = wH + OFF_PE + c * 4;
        float acc[4];
        const float base = in_b[c] + pe_b2[c];
#pragma unroll
        for (int r = 0; r < 4; ++r) acc[r] = base;
        for (int kp4 = 0; kp4 < 8; ++kp4) {
            uint4 wi = *(const uint4*)(inH + kp4 * 512);
            uint4 wp = *(const uint4*)(peH + kp4 * 512);
#pragma unroll
            for (int r = 0; r < 4; ++r) {
                const int rr = rh * 4 + r;
                uint4 f = *(const uint4*)(&FHp[rr * 32 + kp4 * 4]);
                uint4 h = *(const uint4*)(&HHp[rr * 32 + kp4 * 4]);
                acc[r] = dot2(f.x, wi.x, acc[r]); acc[r] = dot2(f.y, wi.y, acc[r]);
                acc[r] = dot2(f.z, wi.z, acc[r]); acc[r] = dot2(f.w, wi.w, acc[r]);
                acc[r] = dot2(h.x, wp.x, acc[r]); acc[r] = dot2(h.y, wp.y, acc[r]);
                acc[r] = dot2(h.z, wp.z, acc[r]); acc[r] = dot2(h.w, wp.w, acc[r]);
            }
        }
#pragma unroll
        for (int r = 0; r < 4; ++r) {
            src[(r0 + rh * 4 + r) * 128 + c] = acc[r];
            S[(rh * 4 + r) * 128 + c] = acc[r];
        }
    }
    __syncthreads();
    // pack S -> SH (pairs along the col axis, which is K for q/k/v)
    for (int i = tid; i < 512; i += 256) {
        float2 s = *(const float2*)(&S[i * 2]);
        SH[i] = pack2(s.x, s.y);
    }
    __syncthreads();
    // q/k/v in one pass: 3 coalesced uint4 tile streams, dot2
    {
        const unsigned* qH = wH + OFF_Q + c * 4;   // + kp4*512
        const unsigned* kH = wH + OFF_K + c * 4;
        const unsigned* vH = wH + OFF_V + c * 4;
        float aq[4], ak[4], av[4];
#pragma unroll
        for (int r = 0; r < 4; ++r) { aq[r] = 0.f; ak[r] = 0.f; av[r] = 0.f; }
        for (int kp4 = 0; kp4 < 16; ++kp4) {
            uint4 wq = *(const uint4*)(qH + kp4 * 512);
            uint4 wk = *(const uint4*)(kH + kp4 * 512);
            uint4 wv = *(const uint4*)(vH + kp4 * 512);
#pragma unroll
            for (int r = 0; r < 4; ++r) {
                uint4 s4 = *(const uint4*)(&SH[(rh * 4 + r) * 64 + kp4 * 4]);
                aq[r] = dot2(s4.x, wq.x, aq[r]); aq[r] = dot2(s4.y, wq.y, aq[r]);
                aq[r] = dot2(s4.z, wq.z, aq[r]); aq[r] = dot2(s4.w, wq.w, aq[r]);
                ak[r] = dot2(s4.x, wk.x, ak[r]); ak[r] = dot2(s4.y, wk.y, ak[r]);
                ak[r] = dot2(s4.z, wk.z, ak[r]); ak[r] = dot2(s4.w, wk.w, ak[r]);
                av[r] = dot2(s4.x, wv.x, av[r]); av[r] = dot2(s4.y, wv.y, av[r]);
                av[r] = dot2(s4.z, wv.z, av[r]); av[r] = dot2(s4.w, wv.w, av[r]);
            }
        }
#pragma unroll
        for (int r = 0; r < 4; ++r) {
            qs[(r0 + rh * 4 + r) * 128 + c] = aq[r];
            ks[(r0 + rh * 4 + r) * 128 + c] = ak[r];
            vs[(r0 + rh * 4 + r) * 128 + c] = av[r];
        }
    }
}

// ---------------------------------------------------------------------------
// K4: attention + o-proj + LN1 + FFN + LN2 + fusion + BN partials.
// Round-6 structure; weight streams = coalesced uint4 tile loads.
// ---------------------------------------------------------------------------
DEVFN void ln_rows8_pack(float* Cb, unsigned* CHp, const float* __restrict__ g,
                         const float* __restrict__ b, int tid)
{
    const int r = tid >> 5, l = tid & 31;
    float x[4]; float s = 0.f, s2 = 0.f;
#pragma unroll
    for (int i = 0; i < 4; ++i) {
        x[i] = Cb[r * 128 + l * 4 + i];
        s += x[i]; s2 += x[i] * x[i];
    }
#pragma unroll
    for (int o = 1; o < 32; o <<= 1) { s += __shfl_xor(s, o); s2 += __shfl_xor(s2, o); }
    float mu = s * (1.f / 128.f);
    float var = s2 * (1.f / 128.f) - mu * mu;
    float rstd = rsqrtf(var + 1e-5f);
    float y[4];
#pragma unroll
    for (int i = 0; i < 4; ++i) {
        int cc = l * 4 + i;
        y[i] = (x[i] - mu) * rstd * g[cc] + b[cc];
        Cb[r * 128 + cc] = y[i];
    }
    CHp[r * 64 + l * 2]     = pack2(y[0], y[1]);
    CHp[r * 64 + l * 2 + 1] = pack2(y[2], y[3]);
}

__global__ __launch_bounds__(256, 4) void k4_main_cst(
    const float* __restrict__ features, const float* __restrict__ src,
    const float* __restrict__ qs, const float* __restrict__ ks, const float* __restrict__ vs,
    const int* __restrict__ nbr,
    const float* __restrict__ q_b, const float* __restrict__ k_b,
    const float* __restrict__ v_b,
    const unsigned* __restrict__ wH,
    const float* __restrict__ o_b,
    const float* __restrict__ n1_g, const float* __restrict__ n1_b,
    const float* __restrict__ l1_b,
    const float* __restrict__ l2_b,
    const float* __restrict__ n3_g, const float* __restrict__ n3_b,
    const float* __restrict__ fu_b,
    float* __restrict__ fused, float* __restrict__ bnSum, float* __restrict__ bnSq)
{
    __shared__ __align__(16) float A[1024];        // src tile; P5 BN staging
    __shared__ __align__(16) float C[1024];        // running activation f32
    __shared__ __align__(16) float Q[1024];        // q rows (bias applied)
    __shared__ __align__(16) float SC[512];        // attention scores
    __shared__ __align__(16) unsigned BtH[512];    // head_out packed 8x64
    __shared__ __align__(16) unsigned CH[512];     // tgt packed 8x64
    __shared__ __align__(16) unsigned FH[256];     // features packed 8x32
    __shared__ __align__(16) _Float16 Hh[2048];    // ffn hidden f16 8x256
    __shared__ __align__(16) float bK[128], bV[128];
    __shared__ int idxL[128];
    const int tid = threadIdx.x;
    const int r0 = blockIdx.x * 8;

    for (int i = tid; i < 1024; i += 256) A[i] = src[r0 * 128 + i];
    if (tid < 256) {
        float2 f = *(const float2*)(features + r0 * 64 + tid * 2);
        FH[tid] = pack2(f.x, f.y);
    }
    if (tid < 128) {
        idxL[tid] = nbr[r0 * 16 + tid];
        bK[tid] = k_b[tid]; bV[tid] = v_b[tid];
    }
    __syncthreads();
    {   // vectorized Q gather + bias: thread = (row=tid>>5, colgroup=tid&31)
        int r = tid >> 5, cg = tid & 31;
        int i0 = idxL[r * 16];
        float4 qv = make_float4(0.f, 0.f, 0.f, 0.f);
        if (i0 >= 0) qv = *(const float4*)(qs + i0 * 128 + cg * 4);
        float4 qb = *(const float4*)(q_b + cg * 4);
        qv.x += qb.x; qv.y += qb.y; qv.z += qb.z; qv.w += qb.w;
        *(float4*)(&Q[r * 128 + cg * 4]) = qv;
    }
    __syncthreads();

    // ---- phase 1a: scores. thread = (row r, head h, group g of 8) --------
    // s_j = q.(k_j + kb) = q.k_j + q.kb ; q.kb hoisted (same ch for both j).
    const int ar = tid >> 5, ah = (tid >> 3) & 3, ag = tid & 7;
    {
        const int ch = ag & 3;
        float sbias = 0.f;
#pragma unroll
        for (int c4 = 0; c4 < 8; ++c4) {
            float4 qv = *(const float4*)(&Q[ar * 128 + ah * 32 + c4 * 4]);
            float4 kb = *(const float4*)(&bK[ch * 32 + c4 * 4]);
            sbias += qv.x * kb.x + qv.y * kb.y + qv.z * kb.z + qv.w * kb.w;
        }
#pragma unroll
        for (int jj = 0; jj < 2; ++jj) {
            int j = ag + jj * 8;
            int j4 = j >> 2;
            int id = idxL[ar * 16 + ah * 4 + j4];
            float s = 0.f;
            if (id >= 0) {
#pragma unroll
                for (int c4 = 0; c4 < 8; ++c4) {
                    float4 qv = *(const float4*)(&Q[ar * 128 + ah * 32 + c4 * 4]);
                    float4 kv = *(const float4*)(ks + id * 128 + ch * 32 + c4 * 4);
                    s += qv.x * kv.x + qv.y * kv.y + qv.z * kv.z + qv.w * kv.w;
                }
            }
            SC[ar * 64 + ah * 16 + j] = (s + sbias) * 0.08838834764831845f;
        }
    }
    __syncthreads();

    // ---- phase 1b: softmax + P@V (sum w = 1 => +vb once); packed write ---
    {
        float p[16];
        float mx = -3.4e38f;
#pragma unroll
        for (int j = 0; j < 16; ++j) { p[j] = SC[ar * 64 + ah * 16 + j]; mx = fmaxf(mx, p[j]); }
        float sum = 0.f;
#pragma unroll
        for (int j = 0; j < 16; ++j) { p[j] = __expf(p[j] - mx); sum += p[j]; }
        float inv = 1.f / sum;
        float4 acc = make_float4(0.f, 0.f, 0.f, 0.f);
#pragma unroll
        for (int j = 0; j < 16; ++j) {
            int j4 = j >> 2, ch = j & 3;
            int id = idxL[ar * 16 + ah * 4 + j4];
            float w = p[j] * inv;
            if (id >= 0) {
                float4 vv = *(const float4*)(vs + id * 128 + ch * 32 + ag * 4);
                acc.x += w * vv.x; acc.y += w * vv.y;
                acc.z += w * vv.z; acc.w += w * vv.w;
            }
        }
        float4 vb = *(const float4*)(&bV[ah * 32 + ag * 4]);
        acc.x += vb.x; acc.y += vb.y; acc.z += vb.z; acc.w += vb.w;
        BtH[ar * 64 + ah * 16 + ag * 2]     = pack2(acc.x, acc.y);
        BtH[ar * 64 + ah * 16 + ag * 2 + 1] = pack2(acc.z, acc.w);
    }
    __syncthreads();

    // ---- phase 2: C = A + head_out @ o_w + o_b (tile uint4 w) ------------
    {
        const int c = tid & 127, rh = tid >> 7;
        const unsigned* oH = wH + OFF_O + c * 4;   // + kp4*512
        float acc[4];
#pragma unroll
        for (int r = 0; r < 4; ++r) acc[r] = 0.f;
        for (int kp4 = 0; kp4 < 16; ++kp4) {
            uint4 w = *(const uint4*)(oH + kp4 * 512);
#pragma unroll
            for (int r = 0; r < 4; ++r) {
                uint4 t = *(const uint4*)(&BtH[(rh * 4 + r) * 64 + kp4 * 4]);
                acc[r] = dot2(t.x, w.x, acc[r]); acc[r] = dot2(t.y, w.y, acc[r]);
                acc[r] = dot2(t.z, w.z, acc[r]); acc[r] = dot2(t.w, w.w, acc[r]);
            }
        }
        const float ob = o_b[c];
#pragma unroll
        for (int r = 0; r < 4; ++r) {
            const int rr = rh * 4 + r;
            C[rr * 128 + c] = A[rr * 128 + c] + ob + acc[r];
        }
    }
    __syncthreads();
    ln_rows8_pack(C, CH, n1_g, n1_b, tid);   // C = tgt (f32 + packed)
    __syncthreads();

    // ---- phase 3: Hh = relu(CH @ l1_w + l1_b)  [8 x 256] f16 out ---------
    {
        const int f = tid;
        const unsigned* l1H = wH + OFF_L1 + f * 4;   // + kp4*1024 (C=256)
        float acc[8];
#pragma unroll
        for (int r = 0; r < 8; ++r) acc[r] = 0.f;
        for (int kp4 = 0; kp4 < 16; ++kp4) {
            uint4 w = *(const uint4*)(l1H + kp4 * 1024);
#pragma unroll
            for (int r = 0; r < 8; ++r) {
                uint4 t = *(const uint4*)(&CH[r * 64 + kp4 * 4]);
                acc[r] = dot2(t.x, w.x, acc[r]); acc[r] = dot2(t.y, w.y, acc[r]);
                acc[r] = dot2(t.z, w.z, acc[r]); acc[r] = dot2(t.w, w.w, acc[r]);
            }
        }
        const float bb = l1_b[f];
#pragma unroll
        for (int r = 0; r < 8; ++r) Hh[r * 256 + f] = (_Float16)relu(acc[r] + bb);
    }
    __syncthreads();

    // ---- phase 4: C += Hh @ l2_w + l2_b (K=256, tile uint4 w) ------------
    {
        const int c = tid & 127, rh = tid >> 7;
        const unsigned* l2H = wH + OFF_L2 + c * 4;   // + kp4*512, kp4 0..31
        const unsigned* HhU = (const unsigned*)Hh;   // 8 x 128 dwords
        float acc[4];
#pragma unroll
        for (int r = 0; r < 4; ++r) acc[r] = 0.f;
        for (int kp4 = 0; kp4 < 32; ++kp4) {
            uint4 w = *(const uint4*)(l2H + kp4 * 512);
#pragma unroll
            for (int r = 0; r < 4; ++r) {
                uint4 t = *(const uint4*)(&HhU[(rh * 4 + r) * 128 + kp4 * 4]);
                acc[r] = dot2(t.x, w.x, acc[r]); acc[r] = dot2(t.y, w.y, acc[r]);
                acc[r] = dot2(t.z, w.z, acc[r]); acc[r] = dot2(t.w, w.w, acc[r]);
            }
        }
        const float lb = l2_b[c];
#pragma unroll
        for (int r = 0; r < 4; ++r) {
            const int rr = rh * 4 + r;
            C[rr * 128 + c] += lb + acc[r];
        }
    }
    __syncthreads();
    ln_rows8_pack(C, CH, n3_g, n3_b, tid);   // C = final tgt (f32 + packed)
    __syncthreads();

    // ---- phase 5: fused = [F, C] @ fu_w + fu_b; BN staging in A ----------
    {
        const int c = tid & 63, rg = tid >> 6;   // 4 groups x 2 rows
        const unsigned* fuH = wH + OFF_FU + c * 4;   // + kp4*256 (C=64)
        float acc[2];
        const float fb = fu_b[c];
#pragma unroll
        for (int r = 0; r < 2; ++r) acc[r] = fb;
        for (int kp4 = 0; kp4 < 8; ++kp4) {      // features half: kp4 0..7
            uint4 w = *(const uint4*)(fuH + kp4 * 256);
#pragma unroll
            for (int r = 0; r < 2; ++r) {
                uint4 t = *(const uint4*)(&FH[(rg * 2 + r) * 32 + kp4 * 4]);
                acc[r] = dot2(t.x, w.x, acc[r]); acc[r] = dot2(t.y, w.y, acc[r]);
                acc[r] = dot2(t.z, w.z, acc[r]); acc[r] = dot2(t.w, w.w, acc[r]);
            }
        }
        for (int kp4 = 0; kp4 < 16; ++kp4) {     // tgt half: kp4 8..23
            uint4 w = *(const uint4*)(fuH + (8 + kp4) * 256);
#pragma unroll
            for (int r = 0; r < 2; ++r) {
                uint4 t = *(const uint4*)(&CH[(rg * 2 + r) * 64 + kp4 * 4]);
                acc[r] = dot2(t.x, w.x, acc[r]); acc[r] = dot2(t.y, w.y, acc[r]);
                acc[r] = dot2(t.z, w.z, acc[r]); acc[r] = dot2(t.w, w.w, acc[r]);
            }
        }
#pragma unroll
        for (int r = 0; r < 2; ++r) {
            int row = rg * 2 + r;
            float v = acc[r];
            fused[(r0 + row) * 64 + c] = v;
            A[row * 64 + c] = v;
        }
    }
    __syncthreads();
    if (tid < 64) {
        float s = 0.f, s2 = 0.f;
#pragma unroll
        for (int r = 0; r < 8; ++r) { float x = A[r * 64 + tid]; s += x; s2 += x * x; }
        atomicAdd(&bnSum[tid], s);
        atomicAdd(&bnSq[tid], s2);
    }
}

// ---------------------------------------------------------------------------
// K5: batchnorm (train-mode stats) + relu -> fp32 out
// ---------------------------------------------------------------------------
__global__ __launch_bounds__(256) void k5_bn_cst(
    const float* __restrict__ fused, const float* __restrict__ bnSum,
    const float* __restrict__ bnSq,
    const float* __restrict__ g, const float* __restrict__ b,
    float* __restrict__ out, int N)
{
    const int total = N * 64;
    const float invN = 1.f / (float)N;
    for (int i = blockIdx.x * 256 + threadIdx.x; i < total; i += gridDim.x * 256) {
        int c = i & 63;
        float mu = bnSum[c] * invN;
        float var = bnSq[c] * invN - mu * mu;
        float x = fused[i];
        float y = (x - mu) * rsqrtf(var + 1e-3f) * g[c] + b[c];
        out[i] = relu(y);
    }
}

// ---------------------------------------------------------------------------
extern "C" void kernel_launch(void* const* d_in, const int* in_sizes, int n_in,
                              void* d_out, int out_size, void* d_ws, size_t ws_size,
                              hipStream_t stream)
{
    const float* features = (const float*)d_in[0];
    const int*   coords   = (const int*)d_in[1];
    const float* pe_w1 = (const float*)d_in[2];
    const float* pe_b1 = (const float*)d_in[3];
    const float* pe_w2 = (const float*)d_in[4];
    const float* pe_b2 = (const float*)d_in[5];
    const float* in_w  = (const float*)d_in[6];
    const float* in_b  = (const float*)d_in[7];
    const float* q_w   = (const float*)d_in[8];
    const float* q_b   = (const float*)d_in[9];
    const float* k_w   = (const float*)d_in[10];
    const float* k_b   = (const float*)d_in[11];
    const float* v_w   = (const float*)d_in[12];
    const float* v_b   = (const float*)d_in[13];
    const float* o_w   = (const float*)d_in[14];
    const float* o_b   = (const float*)d_in[15];
    const float* n1_g  = (const float*)d_in[16];
    const float* n1_b  = (const float*)d_in[17];
    const float* l1_w  = (const float*)d_in[18];
    const float* l1_b  = (const float*)d_in[19];
    const float* l2_w  = (const float*)d_in[20];
    const float* l2_b  = (const float*)d_in[21];
    const float* n3_g  = (const float*)d_in[22];
    const float* n3_b  = (const float*)d_in[23];
    const float* fu_w  = (const float*)d_in[24];
    const float* fu_b  = (const float*)d_in[25];
    const float* bn_g  = (const float*)d_in[26];
    const float* bn_b  = (const float*)d_in[27];

    const int N = in_sizes[0] / 64;   // 8192

    float* src   = (float*)d_ws;            // N*128
    float* qs    = src + (size_t)N * 128;   // N*128
    float* ks    = qs  + (size_t)N * 128;   // N*128
    float* vs    = ks  + (size_t)N * 128;   // N*128
    float* fused = vs  + (size_t)N * 128;   // N*64
    int*   nbr    = (int*)(fused + (size_t)N * 64);   // N*16 ints
    float* bnSum  = (float*)(nbr + (size_t)N * 16);   // 64
    float* bnSq   = bnSum + 64;                       // 64 (contiguous 128)
    unsigned* wH  = (unsigned*)(bnSq + 64);           // packed weights (~320 KB)
    unsigned* pcoords = wH + PACKED_TOTAL;            // N packed byte-coords

    k0_pack<<<64, 256, 0, stream>>>(q_w, k_w, v_w, o_w, l1_w, l2_w,
                                    in_w, pe_w2, fu_w, coords, wH, pcoords, N);
    ka_pre_cst<<<N / 8 + N / 16, 256, 0, stream>>>(features, coords, pcoords,
                                                   pe_w1, pe_b1, pe_b2, in_b,
                                                   wH,
                                                   src, qs, ks, vs, nbr, bnSum, N);
    k4_main_cst<<<N / 8, 256, 0, stream>>>(features, src, qs, ks, vs, nbr,
                                           q_b, k_b, v_b, wH, o_b, n1_g, n1_b,
                                           l1_b, l2_b, n3_g, n3_b,
                                           fu_b, fused, bnSum, bnSq);
    k5_bn_cst<<<512, 256, 0, stream>>>(fused, bnSum, bnSq, bn_g, bn_b,
                                       (float*)d_out, N);
}

// Round 13
// 192.842 us; speedup vs baseline: 2.8597x; 1.0194x over previous
//
#include <hip/hip_runtime.h>

#define DEVFN __device__ __forceinline__

// NaN-propagating relu (fmaxf(NaN,0)==0 would mask upstream failures).
DEVFN float relu(float x) { return x < 0.f ? 0.f : x; }

// f16 pair helpers: weights/activations packed as half2 in k-major pairs.
// v_dot2_f32_f16: 2 MACs per instr, f32 accumulate.
typedef _Float16 h2 __attribute__((ext_vector_type(2)));
DEVFN float dot2(unsigned a, unsigned b, float c) {
    return __builtin_amdgcn_fdot2(__builtin_bit_cast(h2, a),
                                  __builtin_bit_cast(h2, b), c, false);
}
DEVFN unsigned pack2(float x, float y) {
    h2 h; h.x = (_Float16)x; h.y = (_Float16)y;
    return __builtin_bit_cast(unsigned, h);
}
DEVFN float2 unpk(unsigned u) {
    h2 h = __builtin_bit_cast(h2, u);
    return make_float2((float)h.x, (float)h.y);
}

// Manhattan distance of byte-packed coords (x|y<<8|z<<16): one v_sad_u8.
DEVFN unsigned sad3(unsigned a, unsigned b) {
#if __has_builtin(__builtin_amdgcn_sad_u8)
    return __builtin_amdgcn_sad_u8(a, b, 0u);
#else
    int dx = (int)(a & 255u) - (int)(b & 255u); dx = dx < 0 ? -dx : dx;
    int dy = (int)((a >> 8) & 255u) - (int)((b >> 8) & 255u); dy = dy < 0 ? -dy : dy;
    int dz = (int)((a >> 16) & 255u) - (int)((b >> 16) & 255u); dz = dz < 0 ? -dz : dz;
    return (unsigned)(dx + dy + dz);
#endif
}

// Packed-weight layout (round-8 interleaved tile [kp4][c][kp_in], proven):
//   d[kp4*(C*4) + c*4 + (kp&3)] = half2(W[2kp][c], W[2kp+1][c])
#define OFF_Q   0
#define OFF_K   8192
#define OFF_V   16384
#define OFF_O   24576
#define OFF_L1  32768
#define OFF_L2  49152
#define OFF_IN  65536
#define OFF_PE  69632
#define OFF_FU  73728
#define PACKED_TOTAL 79872

// ---------------------------------------------------------------------------
// K0: pack all weight matrices to half2 tiles + coords to bytes (runs once).
// ---------------------------------------------------------------------------
__global__ __launch_bounds__(256) void k0_pack(
    const float* __restrict__ q_w, const float* __restrict__ k_w,
    const float* __restrict__ v_w, const float* __restrict__ o_w,
    const float* __restrict__ l1_w, const float* __restrict__ l2_w,
    const float* __restrict__ in_w, const float* __restrict__ pe_w2,
    const float* __restrict__ fu_w, const int* __restrict__ coords,
    unsigned* __restrict__ dst, unsigned* __restrict__ pcoords, int N)
{
    const int gid = blockIdx.x * 256 + threadIdx.x;
    const int stride = gridDim.x * 256;
    auto packmat = [&](const float* s, int K, int C, unsigned* d) {
        const int kp2 = K / 2;
        const int n = kp2 * C;
        const int c4 = C * 4;
        for (int i = gid; i < n; i += stride) {
            int kp4 = i / c4;
            int rem = i - kp4 * c4;
            int c = rem >> 2, ki = rem & 3;
            int kp = kp4 * 4 + ki;
            d[i] = pack2(s[(2 * kp) * C + c], s[(2 * kp + 1) * C + c]);
        }
    };
    packmat(q_w, 128, 128, dst + OFF_Q);
    packmat(k_w, 128, 128, dst + OFF_K);
    packmat(v_w, 128, 128, dst + OFF_V);
    packmat(o_w, 128, 128, dst + OFF_O);
    packmat(l1_w, 128, 256, dst + OFF_L1);
    packmat(l2_w, 256, 128, dst + OFF_L2);
    packmat(in_w, 64, 128, dst + OFF_IN);
    packmat(pe_w2, 64, 128, dst + OFF_PE);
    packmat(fu_w, 192, 64, dst + OFF_FU);
    for (int i = gid; i < N; i += stride) {
        unsigned x = (unsigned)coords[i * 3 + 0];
        unsigned y = (unsigned)coords[i * 3 + 1];
        unsigned z = (unsigned)coords[i * 3 + 2];
        pcoords[i] = x | (y << 8) | (z << 16);
    }
}

// ---------------------------------------------------------------------------
// KA: fused pre-work, two block roles interleaved (bx%3): 2/3 src, 1/3 nbr.
// qs/ks/vs are stored f16-PACKED (64 dwords/row): halves ka's write traffic
// and halves k4's gather bytes/lines (its dominant latency source).
// Packed write via __shfl_xor(.,1): c-parity == lane-parity in both waves.
// ---------------------------------------------------------------------------
__global__ __launch_bounds__(256, 4) void ka_pre_cst(
    const float* __restrict__ features, const int* __restrict__ coords,
    const unsigned* __restrict__ pcoords,
    const float* __restrict__ pe_w1, const float* __restrict__ pe_b1,
    const float* __restrict__ pe_b2,
    const float* __restrict__ in_b,
    const unsigned* __restrict__ wH,          // packed weights
    float* __restrict__ src,
    unsigned* __restrict__ qs, unsigned* __restrict__ ks, unsigned* __restrict__ vs,
    int* __restrict__ nbr, float* __restrict__ bnAcc, int N)
{
    // src-role LDS
    __shared__ __align__(16) float S[1024];       // 8 x 128 src f32
    __shared__ __align__(16) unsigned SH[512];    // 8 x 64 src packed
    __shared__ __align__(16) unsigned FHp[256];   // 8 x 32 features packed
    __shared__ __align__(16) unsigned HHp[256];   // 8 x 32 pe-hidden packed
    __shared__ int   sC[24];
    // nbr-role LDS
    __shared__ int cnt[16];
    __shared__ int lst[16 * 64];
    __shared__ int outL[256];

    const int tid = threadIdx.x;
    const int bx = blockIdx.x;
    const int role_nbr = (bx % 3) == 2;

    if (role_nbr) {
        // ---------------- nbr role: neighbor search -----------------------
        const int nb = bx / 3;
        const int q0 = nb * 16;
        if (nb == 0 && tid < 128) bnAcc[tid] = 0.f;
        if (tid < 16) cnt[tid] = 0;
        outL[tid] = -1;
        __syncthreads();
        unsigned pq[16];
#pragma unroll
        for (int q = 0; q < 16; ++q) pq[q] = pcoords[q0 + q];
        for (int cd = tid; cd < N; cd += 256) {
            unsigned pcv = pcoords[cd];
#pragma unroll
            for (int q = 0; q < 16; ++q) {
                unsigned d = sad3(pcv, pq[q]);
                if (d <= 4u) {
                    int s = atomicAdd(&cnt[q], 1);
                    if (s < 64) lst[q * 64 + s] = ((int)d << 13) | cd;
                }
            }
        }
        __syncthreads();
        {
            const int q = tid >> 4, t = tid & 15;
            int n = cnt[q]; if (n > 64) n = 64;
            for (int e = t; e < n; e += 16) {
                int key = lst[q * 64 + e];
                int rank = 0;
                for (int j = 0; j < n; ++j) rank += (lst[q * 64 + j] < key) ? 1 : 0;
                if (rank < 16) outL[q * 16 + rank] = key & 8191;
            }
        }
        __syncthreads();
        {
            const int q = tid >> 4, t = tid & 15;
            nbr[(q0 + q) * 16 + t] = outL[q * 16 + t];
        }
        return;
    }

    // ---------------- src role: src + q/k/v projections -------------------
    const int sb = (bx / 3) * 2 + (bx % 3);   // 0..1023
    const int r0 = sb * 8;
    if (tid < 24) sC[tid] = coords[r0 * 3 + tid];
    if (tid < 256) {   // features 8x64 -> packed pairs
        float2 f = *(const float2*)(features + r0 * 64 + tid * 2);
        FHp[tid] = pack2(f.x, f.y);
    }
    __syncthreads();
    if (tid < 256) {   // pe hidden, 2 cols per thread, packed
        int r = tid >> 5, t2 = (tid & 31) * 2;
        float v0 = sC[r * 3 + 0] * (1.f / 95.f);
        float v1 = sC[r * 3 + 1] * (1.f / 95.f);
        float v2 = sC[r * 3 + 2] * (1.f / 95.f);
        float h0 = v0 * pe_w1[t2] + v1 * pe_w1[64 + t2] + v2 * pe_w1[128 + t2] + pe_b1[t2];
        float h1 = v0 * pe_w1[t2 + 1] + v1 * pe_w1[64 + t2 + 1] + v2 * pe_w1[128 + t2 + 1] + pe_b1[t2 + 1];
        HHp[tid] = pack2(relu(h0), relu(h1));
    }
    __syncthreads();
    const int c = tid & 127, rh = tid >> 7;
    {
        // src = F@in_w + H@pe_w2 + (in_b + pe_b2); tile uint4 weights
        const unsigned* inH = wH + OFF_IN + c * 4;   // + kp4*512
        const unsigned* peH = wH + OFF_PE + c * 4;
        float acc[4];
        const float base = in_b[c] + pe_b2[c];
#pragma unroll
        for (int r = 0; r < 4; ++r) acc[r] = base;
        for (int kp4 = 0; kp4 < 8; ++kp4) {
            uint4 wi = *(const uint4*)(inH + kp4 * 512);
            uint4 wp = *(const uint4*)(peH + kp4 * 512);
#pragma unroll
            for (int r = 0; r < 4; ++r) {
                const int rr = rh * 4 + r;
                uint4 f = *(const uint4*)(&FHp[rr * 32 + kp4 * 4]);
                uint4 h = *(const uint4*)(&HHp[rr * 32 + kp4 * 4]);
                acc[r] = dot2(f.x, wi.x, acc[r]); acc[r] = dot2(f.y, wi.y, acc[r]);
                acc[r] = dot2(f.z, wi.z, acc[r]); acc[r] = dot2(f.w, wi.w, acc[r]);
                acc[r] = dot2(h.x, wp.x, acc[r]); acc[r] = dot2(h.y, wp.y, acc[r]);
                acc[r] = dot2(h.z, wp.z, acc[r]); acc[r] = dot2(h.w, wp.w, acc[r]);
            }
        }
#pragma unroll
        for (int r = 0; r < 4; ++r) {
            src[(r0 + rh * 4 + r) * 128 + c] = acc[r];
            S[(rh * 4 + r) * 128 + c] = acc[r];
        }
    }
    __syncthreads();
    // pack S -> SH (pairs along the col axis, which is K for q/k/v)
    for (int i = tid; i < 512; i += 256) {
        float2 s = *(const float2*)(&S[i * 2]);
        SH[i] = pack2(s.x, s.y);
    }
    __syncthreads();
    // q/k/v in one pass: 3 coalesced uint4 tile streams, dot2; packed store
    {
        const unsigned* qH = wH + OFF_Q + c * 4;   // + kp4*512
        const unsigned* kH = wH + OFF_K + c * 4;
        const unsigned* vH = wH + OFF_V + c * 4;
        float aq[4], ak[4], av[4];
#pragma unroll
        for (int r = 0; r < 4; ++r) { aq[r] = 0.f; ak[r] = 0.f; av[r] = 0.f; }
        for (int kp4 = 0; kp4 < 16; ++kp4) {
            uint4 wq = *(const uint4*)(qH + kp4 * 512);
            uint4 wk = *(const uint4*)(kH + kp4 * 512);
            uint4 wv = *(const uint4*)(vH + kp4 * 512);
#pragma unroll
            for (int r = 0; r < 4; ++r) {
                uint4 s4 = *(const uint4*)(&SH[(rh * 4 + r) * 64 + kp4 * 4]);
                aq[r] = dot2(s4.x, wq.x, aq[r]); aq[r] = dot2(s4.y, wq.y, aq[r]);
                aq[r] = dot2(s4.z, wq.z, aq[r]); aq[r] = dot2(s4.w, wq.w, aq[r]);
                ak[r] = dot2(s4.x, wk.x, ak[r]); ak[r] = dot2(s4.y, wk.y, ak[r]);
                ak[r] = dot2(s4.z, wk.z, ak[r]); ak[r] = dot2(s4.w, wk.w, ak[r]);
                av[r] = dot2(s4.x, wv.x, av[r]); av[r] = dot2(s4.y, wv.y, av[r]);
                av[r] = dot2(s4.z, wv.z, av[r]); av[r] = dot2(s4.w, wv.w, av[r]);
            }
        }
#pragma unroll
        for (int r = 0; r < 4; ++r) {
            float oq = __shfl_xor(aq[r], 1);
            float ok = __shfl_xor(ak[r], 1);
            float ov = __shfl_xor(av[r], 1);
            if ((c & 1) == 0) {
                const int base = (r0 + rh * 4 + r) * 64 + (c >> 1);
                qs[base] = pack2(aq[r], oq);
                ks[base] = pack2(ak[r], ok);
                vs[base] = pack2(av[r], ov);
            }
        }
    }
}

// ---------------------------------------------------------------------------
// K4: attention + o-proj + LN1 + FFN + LN2 + fusion + BN partials.
// qs/ks/vs gathers now f16-packed: half the bytes/lines per gather.
// ---------------------------------------------------------------------------
DEVFN void ln_rows8_pack(float* Cb, unsigned* CHp, const float* __restrict__ g,
                         const float* __restrict__ b, int tid)
{
    const int r = tid >> 5, l = tid & 31;
    float x[4]; float s = 0.f, s2 = 0.f;
#pragma unroll
    for (int i = 0; i < 4; ++i) {
        x[i] = Cb[r * 128 + l * 4 + i];
        s += x[i]; s2 += x[i] * x[i];
    }
#pragma unroll
    for (int o = 1; o < 32; o <<= 1) { s += __shfl_xor(s, o); s2 += __shfl_xor(s2, o); }
    float mu = s * (1.f / 128.f);
    float var = s2 * (1.f / 128.f) - mu * mu;
    float rstd = rsqrtf(var + 1e-5f);
    float y[4];
#pragma unroll
    for (int i = 0; i < 4; ++i) {
        int cc = l * 4 + i;
        y[i] = (x[i] - mu) * rstd * g[cc] + b[cc];
        Cb[r * 128 + cc] = y[i];
    }
    CHp[r * 64 + l * 2]     = pack2(y[0], y[1]);
    CHp[r * 64 + l * 2 + 1] = pack2(y[2], y[3]);
}

__global__ __launch_bounds__(256, 4) void k4_main_cst(
    const float* __restrict__ features, const float* __restrict__ src,
    const unsigned* __restrict__ qs, const unsigned* __restrict__ ks,
    const unsigned* __restrict__ vs,
    const int* __restrict__ nbr,
    const float* __restrict__ q_b, const float* __restrict__ k_b,
    const float* __restrict__ v_b,
    const unsigned* __restrict__ wH,
    const float* __restrict__ o_b,
    const float* __restrict__ n1_g, const float* __restrict__ n1_b,
    const float* __restrict__ l1_b,
    const float* __restrict__ l2_b,
    const float* __restrict__ n3_g, const float* __restrict__ n3_b,
    const float* __restrict__ fu_b,
    float* __restrict__ fused, float* __restrict__ bnSum, float* __restrict__ bnSq)
{
    __shared__ __align__(16) float A[1024];        // src tile; P5 BN staging
    __shared__ __align__(16) float C[1024];        // running activation f32
    __shared__ __align__(16) float Q[1024];        // q rows f32 (bias applied)
    __shared__ __align__(16) unsigned QH[512];     // q rows packed 8x64
    __shared__ __align__(16) float SC[512];        // attention scores
    __shared__ __align__(16) unsigned BtH[512];    // head_out packed 8x64
    __shared__ __align__(16) unsigned CH[512];     // tgt packed 8x64
    __shared__ __align__(16) unsigned FH[256];     // features packed 8x32
    __shared__ __align__(16) _Float16 Hh[2048];    // ffn hidden f16 8x256
    __shared__ __align__(16) float bK[128], bV[128];
    __shared__ int idxL[128];
    const int tid = threadIdx.x;
    const int r0 = blockIdx.x * 8;

    for (int i = tid; i < 1024; i += 256) A[i] = src[r0 * 128 + i];
    if (tid < 256) {
        float2 f = *(const float2*)(features + r0 * 64 + tid * 2);
        FH[tid] = pack2(f.x, f.y);
    }
    if (tid < 128) {
        idxL[tid] = nbr[r0 * 16 + tid];
        bK[tid] = k_b[tid]; bV[tid] = v_b[tid];
    }
    __syncthreads();
    if (tid < 128) {   // Q gather + bias: thread = (row=tid>>4, cg=tid&15)
        int r = tid >> 4, cg = tid & 15;
        int i0 = idxL[r * 16];
        uint4 qv = make_uint4(0u, 0u, 0u, 0u);
        if (i0 >= 0) qv = *(const uint4*)(qs + i0 * 64 + cg * 4);
        float2 u0 = unpk(qv.x), u1 = unpk(qv.y), u2 = unpk(qv.z), u3 = unpk(qv.w);
        float4 b0 = *(const float4*)(q_b + cg * 8);
        float4 b1 = *(const float4*)(q_b + cg * 8 + 4);
        float q0 = u0.x + b0.x, q1 = u0.y + b0.y, q2 = u1.x + b0.z, q3 = u1.y + b0.w;
        float q4 = u2.x + b1.x, q5 = u2.y + b1.y, q6 = u3.x + b1.z, q7 = u3.y + b1.w;
        *(float4*)(&Q[r * 128 + cg * 8])     = make_float4(q0, q1, q2, q3);
        *(float4*)(&Q[r * 128 + cg * 8 + 4]) = make_float4(q4, q5, q6, q7);
        QH[r * 64 + cg * 4 + 0] = pack2(q0, q1);
        QH[r * 64 + cg * 4 + 1] = pack2(q2, q3);
        QH[r * 64 + cg * 4 + 2] = pack2(q4, q5);
        QH[r * 64 + cg * 4 + 3] = pack2(q6, q7);
    }
    __syncthreads();

    // ---- phase 1a: scores. thread = (row r, head h, group g of 8) --------
    // s_j = q'.k_j (packed dot2) + q'.kb (f32, hoisted).
    const int ar = tid >> 5, ah = (tid >> 3) & 3, ag = tid & 7;
    {
        const int ch = ag & 3;
        float sbias = 0.f;
#pragma unroll
        for (int c4 = 0; c4 < 8; ++c4) {
            float4 qv = *(const float4*)(&Q[ar * 128 + ah * 32 + c4 * 4]);
            float4 kb = *(const float4*)(&bK[ch * 32 + c4 * 4]);
            sbias += qv.x * kb.x + qv.y * kb.y + qv.z * kb.z + qv.w * kb.w;
        }
#pragma unroll
        for (int jj = 0; jj < 2; ++jj) {
            int j = ag + jj * 8;
            int j4 = j >> 2;
            int id = idxL[ar * 16 + ah * 4 + j4];
            float s = 0.f;
            if (id >= 0) {
                const unsigned* kr = ks + id * 64 + ch * 16;
#pragma unroll
                for (int c4 = 0; c4 < 4; ++c4) {
                    uint4 kv = *(const uint4*)(kr + c4 * 4);
                    uint4 qv = *(const uint4*)(&QH[ar * 64 + ah * 16 + c4 * 4]);
                    s = dot2(qv.x, kv.x, s); s = dot2(qv.y, kv.y, s);
                    s = dot2(qv.z, kv.z, s); s = dot2(qv.w, kv.w, s);
                }
            }
            SC[ar * 64 + ah * 16 + j] = (s + sbias) * 0.08838834764831845f;
        }
    }
    __syncthreads();

    // ---- phase 1b: softmax + P@V (sum w = 1 => +vb once); packed v -------
    {
        float p[16];
        float mx = -3.4e38f;
#pragma unroll
        for (int j = 0; j < 16; ++j) { p[j] = SC[ar * 64 + ah * 16 + j]; mx = fmaxf(mx, p[j]); }
        float sum = 0.f;
#pragma unroll
        for (int j = 0; j < 16; ++j) { p[j] = __expf(p[j] - mx); sum += p[j]; }
        float inv = 1.f / sum;
        float4 acc = make_float4(0.f, 0.f, 0.f, 0.f);
#pragma unroll
        for (int j = 0; j < 16; ++j) {
            int j4 = j >> 2, ch = j & 3;
            int id = idxL[ar * 16 + ah * 4 + j4];
            float w = p[j] * inv;
            if (id >= 0) {
                uint2 vv = *(const uint2*)(vs + id * 64 + ch * 16 + ag * 2);
                float2 v01 = unpk(vv.x), v23 = unpk(vv.y);
                acc.x += w * v01.x; acc.y += w * v01.y;
                acc.z += w * v23.x; acc.w += w * v23.y;
            }
        }
        float4 vb = *(const float4*)(&bV[ah * 32 + ag * 4]);
        acc.x += vb.x; acc.y += vb.y; acc.z += vb.z; acc.w += vb.w;
        BtH[ar * 64 + ah * 16 + ag * 2]     = pack2(acc.x, acc.y);
        BtH[ar * 64 + ah * 16 + ag * 2 + 1] = pack2(acc.z, acc.w);
    }
    __syncthreads();

    // ---- phase 2: C = A + head_out @ o_w + o_b (tile uint4 w) ------------
    {
        const int c = tid & 127, rh = tid >> 7;
        const unsigned* oH = wH + OFF_O + c * 4;   // + kp4*512
        float acc[4];
#pragma unroll
        for (int r = 0; r < 4; ++r) acc[r] = 0.f;
        for (int kp4 = 0; kp4 < 16; ++kp4) {
            uint4 w = *(const uint4*)(oH + kp4 * 512);
#pragma unroll
            for (int r = 0; r < 4; ++r) {
                uint4 t = *(const uint4*)(&BtH[(rh * 4 + r) * 64 + kp4 * 4]);
                acc[r] = dot2(t.x, w.x, acc[r]); acc[r] = dot2(t.y, w.y, acc[r]);
                acc[r] = dot2(t.z, w.z, acc[r]); acc[r] = dot2(t.w, w.w, acc[r]);
            }
        }
        const float ob = o_b[c];
#pragma unroll
        for (int r = 0; r < 4; ++r) {
            const int rr = rh * 4 + r;
            C[rr * 128 + c] = A[rr * 128 + c] + ob + acc[r];
        }
    }
    __syncthreads();
    ln_rows8_pack(C, CH, n1_g, n1_b, tid);   // C = tgt (f32 + packed)
    __syncthreads();

    // ---- phase 3: Hh = relu(CH @ l1_w + l1_b)  [8 x 256] f16 out ---------
    {
        const int f = tid;
        const unsigned* l1H = wH + OFF_L1 + f * 4;   // + kp4*1024 (C=256)
        float acc[8];
#pragma unroll
        for (int r = 0; r < 8; ++r) acc[r] = 0.f;
        for (int kp4 = 0; kp4 < 16; ++kp4) {
            uint4 w = *(const uint4*)(l1H + kp4 * 1024);
#pragma unroll
            for (int r = 0; r < 8; ++r) {
                uint4 t = *(const uint4*)(&CH[r * 64 + kp4 * 4]);
                acc[r] = dot2(t.x, w.x, acc[r]); acc[r] = dot2(t.y, w.y, acc[r]);
                acc[r] = dot2(t.z, w.z, acc[r]); acc[r] = dot2(t.w, w.w, acc[r]);
            }
        }
        const float bb = l1_b[f];
#pragma unroll
        for (int r = 0; r < 8; ++r) Hh[r * 256 + f] = (_Float16)relu(acc[r] + bb);
    }
    __syncthreads();

    // ---- phase 4: C += Hh @ l2_w + l2_b (K=256, tile uint4 w) ------------
    {
        const int c = tid & 127, rh = tid >> 7;
        const unsigned* l2H = wH + OFF_L2 + c * 4;   // + kp4*512, kp4 0..31
        const unsigned* HhU = (const unsigned*)Hh;   // 8 x 128 dwords
        float acc[4];
#pragma unroll
        for (int r = 0; r < 4; ++r) acc[r] = 0.f;
        for (int kp4 = 0; kp4 < 32; ++kp4) {
            uint4 w = *(const uint4*)(l2H + kp4 * 512);
#pragma unroll
            for (int r = 0; r < 4; ++r) {
                uint4 t = *(const uint4*)(&HhU[(rh * 4 + r) * 128 + kp4 * 4]);
                acc[r] = dot2(t.x, w.x, acc[r]); acc[r] = dot2(t.y, w.y, acc[r]);
                acc[r] = dot2(t.z, w.z, acc[r]); acc[r] = dot2(t.w, w.w, acc[r]);
            }
        }
        const float lb = l2_b[c];
#pragma unroll
        for (int r = 0; r < 4; ++r) {
            const int rr = rh * 4 + r;
            C[rr * 128 + c] += lb + acc[r];
        }
    }
    __syncthreads();
    ln_rows8_pack(C, CH, n3_g, n3_b, tid);   // C = final tgt (f32 + packed)
    __syncthreads();

    // ---- phase 5: fused = [F, C] @ fu_w + fu_b; BN staging in A ----------
    {
        const int c = tid & 63, rg = tid >> 6;   // 4 groups x 2 rows
        const unsigned* fuH = wH + OFF_FU + c * 4;   // + kp4*256 (C=64)
        float acc[2];
        const float fb = fu_b[c];
#pragma unroll
        for (int r = 0; r < 2; ++r) acc[r] = fb;
        for (int kp4 = 0; kp4 < 8; ++kp4) {      // features half: kp4 0..7
            uint4 w = *(const uint4*)(fuH + kp4 * 256);
#pragma unroll
            for (int r = 0; r < 2; ++r) {
                uint4 t = *(const uint4*)(&FH[(rg * 2 + r) * 32 + kp4 * 4]);
                acc[r] = dot2(t.x, w.x, acc[r]); acc[r] = dot2(t.y, w.y, acc[r]);
                acc[r] = dot2(t.z, w.z, acc[r]); acc[r] = dot2(t.w, w.w, acc[r]);
            }
        }
        for (int kp4 = 0; kp4 < 16; ++kp4) {     // tgt half: kp4 8..23
            uint4 w = *(const uint4*)(fuH + (8 + kp4) * 256);
#pragma unroll
            for (int r = 0; r < 2; ++r) {
                uint4 t = *(const uint4*)(&CH[(rg * 2 + r) * 64 + kp4 * 4]);
                acc[r] = dot2(t.x, w.x, acc[r]); acc[r] = dot2(t.y, w.y, acc[r]);
                acc[r] = dot2(t.z, w.z, acc[r]); acc[r] = dot2(t.w, w.w, acc[r]);
            }
        }
#pragma unroll
        for (int r = 0; r < 2; ++r) {
            int row = rg * 2 + r;
            float v = acc[r];
            fused[(r0 + row) * 64 + c] = v;
            A[row * 64 + c] = v;
        }
    }
    __syncthreads();
    if (tid < 64) {
        float s = 0.f, s2 = 0.f;
#pragma unroll
        for (int r = 0; r < 8; ++r) { float x = A[r * 64 + tid]; s += x; s2 += x * x; }
        atomicAdd(&bnSum[tid], s);
        atomicAdd(&bnSq[tid], s2);
    }
}

// ---------------------------------------------------------------------------
// K5: batchnorm (train-mode stats) + relu -> fp32 out
// ---------------------------------------------------------------------------
__global__ __launch_bounds__(256) void k5_bn_cst(
    const float* __restrict__ fused, const float* __restrict__ bnSum,
    const float* __restrict__ bnSq,
    const float* __restrict__ g, const float* __restrict__ b,
    float* __restrict__ out, int N)
{
    const int total = N * 64;
    const float invN = 1.f / (float)N;
    for (int i = blockIdx.x * 256 + threadIdx.x; i < total; i += gridDim.x * 256) {
        int c = i & 63;
        float mu = bnSum[c] * invN;
        float var = bnSq[c] * invN - mu * mu;
        float x = fused[i];
        float y = (x - mu) * rsqrtf(var + 1e-3f) * g[c] + b[c];
        out[i] = relu(y);
    }
}

// ---------------------------------------------------------------------------
extern "C" void kernel_launch(void* const* d_in, const int* in_sizes, int n_in,
                              void* d_out, int out_size, void* d_ws, size_t ws_size,
                              hipStream_t stream)
{
    const float* features = (const float*)d_in[0];
    const int*   coords   = (const int*)d_in[1];
    const float* pe_w1 = (const float*)d_in[2];
    const float* pe_b1 = (const float*)d_in[3];
    const float* pe_w2 = (const float*)d_in[4];
    const float* pe_b2 = (const float*)d_in[5];
    const float* in_w  = (const float*)d_in[6];
    const float* in_b  = (const float*)d_in[7];
    const float* q_w   = (const float*)d_in[8];
    const float* q_b   = (const float*)d_in[9];
    const float* k_w   = (const float*)d_in[10];
    const float* k_b   = (const float*)d_in[11];
    const float* v_w   = (const float*)d_in[12];
    const float* v_b   = (const float*)d_in[13];
    const float* o_w   = (const float*)d_in[14];
    const float* o_b   = (const float*)d_in[15];
    const float* n1_g  = (const float*)d_in[16];
    const float* n1_b  = (const float*)d_in[17];
    const float* l1_w  = (const float*)d_in[18];
    const float* l1_b  = (const float*)d_in[19];
    const float* l2_w  = (const float*)d_in[20];
    const float* l2_b  = (const float*)d_in[21];
    const float* n3_g  = (const float*)d_in[22];
    const float* n3_b  = (const float*)d_in[23];
    const float* fu_w  = (const float*)d_in[24];
    const float* fu_b  = (const float*)d_in[25];
    const float* bn_g  = (const float*)d_in[26];
    const float* bn_b  = (const float*)d_in[27];

    const int N = in_sizes[0] / 64;   // 8192

    float*    src   = (float*)d_ws;                    // N*128 f32
    unsigned* qs    = (unsigned*)(src + (size_t)N * 128);  // N*64 packed
    unsigned* ks    = qs + (size_t)N * 64;             // N*64 packed
    unsigned* vs    = ks + (size_t)N * 64;             // N*64 packed
    float*    fused = (float*)(vs + (size_t)N * 64);   // N*64 f32
    int*      nbr   = (int*)(fused + (size_t)N * 64);  // N*16 ints
    float*    bnSum = (float*)(nbr + (size_t)N * 16);  // 64
    float*    bnSq  = bnSum + 64;                      // 64 (contiguous 128)
    unsigned* wH    = (unsigned*)(bnSq + 64);          // packed weights (~320 KB)
    unsigned* pcoords = wH + PACKED_TOTAL;             // N packed byte-coords

    k0_pack<<<64, 256, 0, stream>>>(q_w, k_w, v_w, o_w, l1_w, l2_w,
                                    in_w, pe_w2, fu_w, coords, wH, pcoords, N);
    ka_pre_cst<<<N / 8 + N / 16, 256, 0, stream>>>(features, coords, pcoords,
                                                   pe_w1, pe_b1, pe_b2, in_b,
                                                   wH,
                                                   src, qs, ks, vs, nbr, bnSum, N);
    k4_main_cst<<<N / 8, 256, 0, stream>>>(features, src, qs, ks, vs, nbr,
                                           q_b, k_b, v_b, wH, o_b, n1_g, n1_b,
                                           l1_b, l2_b, n3_g, n3_b,
                                           fu_b, fused, bnSum, bnSq);
    k5_bn_cst<<<512, 256, 0, stream>>>(fused, bnSum, bnSq, bn_g, bn_b,
                                       (float*)d_out, N);
}

// Round 14
// 192.093 us; speedup vs baseline: 2.8709x; 1.0039x over previous
//
#include <hip/hip_runtime.h>

#define DEVFN __device__ __forceinline__

// NaN-propagating relu (fmaxf(NaN,0)==0 would mask upstream failures).
DEVFN float relu(float x) { return x < 0.f ? 0.f : x; }

// f16 pair helpers: weights/activations packed as half2 in k-major pairs.
// v_dot2_f32_f16: 2 MACs per instr, f32 accumulate.
typedef _Float16 h2 __attribute__((ext_vector_type(2)));
DEVFN float dot2(unsigned a, unsigned b, float c) {
    return __builtin_amdgcn_fdot2(__builtin_bit_cast(h2, a),
                                  __builtin_bit_cast(h2, b), c, false);
}
DEVFN unsigned pack2(float x, float y) {
    h2 h; h.x = (_Float16)x; h.y = (_Float16)y;
    return __builtin_bit_cast(unsigned, h);
}
DEVFN float2 unpk(unsigned u) {
    h2 h = __builtin_bit_cast(h2, u);
    return make_float2((float)h.x, (float)h.y);
}

// Manhattan distance of byte-packed coords (x|y<<8|z<<16): one v_sad_u8.
DEVFN unsigned sad3(unsigned a, unsigned b) {
#if __has_builtin(__builtin_amdgcn_sad_u8)
    return __builtin_amdgcn_sad_u8(a, b, 0u);
#else
    int dx = (int)(a & 255u) - (int)(b & 255u); dx = dx < 0 ? -dx : dx;
    int dy = (int)((a >> 8) & 255u) - (int)((b >> 8) & 255u); dy = dy < 0 ? -dy : dy;
    int dz = (int)((a >> 16) & 255u) - (int)((b >> 16) & 255u); dz = dz < 0 ? -dz : dz;
    return (unsigned)(dx + dy + dz);
#endif
}

// Packed-weight layout (round-8 interleaved tile [kp4][c][kp_in], proven):
//   d[kp4*(C*4) + c*4 + (kp&3)] = half2(W[2kp][c], W[2kp+1][c])
#define OFF_Q   0
#define OFF_K   8192
#define OFF_V   16384
#define OFF_O   24576
#define OFF_L1  32768
#define OFF_L2  49152
#define OFF_IN  65536
#define OFF_PE  69632
#define OFF_FU  73728
#define PACKED_TOTAL 79872

// ---------------------------------------------------------------------------
// K0: pack all weight matrices to half2 tiles + coords to bytes (runs once).
// ---------------------------------------------------------------------------
__global__ __launch_bounds__(256) void k0_pack(
    const float* __restrict__ q_w, const float* __restrict__ k_w,
    const float* __restrict__ v_w, const float* __restrict__ o_w,
    const float* __restrict__ l1_w, const float* __restrict__ l2_w,
    const float* __restrict__ in_w, const float* __restrict__ pe_w2,
    const float* __restrict__ fu_w, const int* __restrict__ coords,
    unsigned* __restrict__ dst, unsigned* __restrict__ pcoords, int N)
{
    const int gid = blockIdx.x * 256 + threadIdx.x;
    const int stride = gridDim.x * 256;
    auto packmat = [&](const float* s, int K, int C, unsigned* d) {
        const int kp2 = K / 2;
        const int n = kp2 * C;
        const int c4 = C * 4;
        for (int i = gid; i < n; i += stride) {
            int kp4 = i / c4;
            int rem = i - kp4 * c4;
            int c = rem >> 2, ki = rem & 3;
            int kp = kp4 * 4 + ki;
            d[i] = pack2(s[(2 * kp) * C + c], s[(2 * kp + 1) * C + c]);
        }
    };
    packmat(q_w, 128, 128, dst + OFF_Q);
    packmat(k_w, 128, 128, dst + OFF_K);
    packmat(v_w, 128, 128, dst + OFF_V);
    packmat(o_w, 128, 128, dst + OFF_O);
    packmat(l1_w, 128, 256, dst + OFF_L1);
    packmat(l2_w, 256, 128, dst + OFF_L2);
    packmat(in_w, 64, 128, dst + OFF_IN);
    packmat(pe_w2, 64, 128, dst + OFF_PE);
    packmat(fu_w, 192, 64, dst + OFF_FU);
    for (int i = gid; i < N; i += stride) {
        unsigned x = (unsigned)coords[i * 3 + 0];
        unsigned y = (unsigned)coords[i * 3 + 1];
        unsigned z = (unsigned)coords[i * 3 + 2];
        pcoords[i] = x | (y << 8) | (z << 16);
    }
}

// ---------------------------------------------------------------------------
// KA: fused pre-work, two block roles interleaved (bx%3): 2/3 src, 1/3 nbr.
// qs/ks/vs stored f16-packed (64 dwords/row). nbr scan via v_sad_u8.
// ---------------------------------------------------------------------------
__global__ __launch_bounds__(256, 4) void ka_pre_cst(
    const float* __restrict__ features, const int* __restrict__ coords,
    const unsigned* __restrict__ pcoords,
    const float* __restrict__ pe_w1, const float* __restrict__ pe_b1,
    const float* __restrict__ pe_b2,
    const float* __restrict__ in_b,
    const unsigned* __restrict__ wH,          // packed weights
    float* __restrict__ src,
    unsigned* __restrict__ qs, unsigned* __restrict__ ks, unsigned* __restrict__ vs,
    int* __restrict__ nbr, float* __restrict__ bnAcc, int N)
{
    // src-role LDS
    __shared__ __align__(16) float S[1024];       // 8 x 128 src f32
    __shared__ __align__(16) unsigned SH[512];    // 8 x 64 src packed
    __shared__ __align__(16) unsigned FHp[256];   // 8 x 32 features packed
    __shared__ __align__(16) unsigned HHp[256];   // 8 x 32 pe-hidden packed
    __shared__ int   sC[24];
    // nbr-role LDS
    __shared__ int cnt[16];
    __shared__ int lst[16 * 64];
    __shared__ int outL[256];

    const int tid = threadIdx.x;
    const int bx = blockIdx.x;
    const int role_nbr = (bx % 3) == 2;

    if (role_nbr) {
        // ---------------- nbr role: neighbor search -----------------------
        const int nb = bx / 3;
        const int q0 = nb * 16;
        if (nb == 0 && tid < 128) bnAcc[tid] = 0.f;
        if (tid < 16) cnt[tid] = 0;
        outL[tid] = -1;
        __syncthreads();
        unsigned pq[16];
#pragma unroll
        for (int q = 0; q < 16; ++q) pq[q] = pcoords[q0 + q];
        for (int cd = tid; cd < N; cd += 256) {
            unsigned pcv = pcoords[cd];
#pragma unroll
            for (int q = 0; q < 16; ++q) {
                unsigned d = sad3(pcv, pq[q]);
                if (d <= 4u) {
                    int s = atomicAdd(&cnt[q], 1);
                    if (s < 64) lst[q * 64 + s] = ((int)d << 13) | cd;
                }
            }
        }
        __syncthreads();
        {
            const int q = tid >> 4, t = tid & 15;
            int n = cnt[q]; if (n > 64) n = 64;
            for (int e = t; e < n; e += 16) {
                int key = lst[q * 64 + e];
                int rank = 0;
                for (int j = 0; j < n; ++j) rank += (lst[q * 64 + j] < key) ? 1 : 0;
                if (rank < 16) outL[q * 16 + rank] = key & 8191;
            }
        }
        __syncthreads();
        {
            const int q = tid >> 4, t = tid & 15;
            nbr[(q0 + q) * 16 + t] = outL[q * 16 + t];
        }
        return;
    }

    // ---------------- src role: src + q/k/v projections -------------------
    const int sb = (bx / 3) * 2 + (bx % 3);   // 0..1023
    const int r0 = sb * 8;
    if (tid < 24) sC[tid] = coords[r0 * 3 + tid];
    if (tid < 256) {   // features 8x64 -> packed pairs
        float2 f = *(const float2*)(features + r0 * 64 + tid * 2);
        FHp[tid] = pack2(f.x, f.y);
    }
    __syncthreads();
    if (tid < 256) {   // pe hidden, 2 cols per thread, packed
        int r = tid >> 5, t2 = (tid & 31) * 2;
        float v0 = sC[r * 3 + 0] * (1.f / 95.f);
        float v1 = sC[r * 3 + 1] * (1.f / 95.f);
        float v2 = sC[r * 3 + 2] * (1.f / 95.f);
        float h0 = v0 * pe_w1[t2] + v1 * pe_w1[64 + t2] + v2 * pe_w1[128 + t2] + pe_b1[t2];
        float h1 = v0 * pe_w1[t2 + 1] + v1 * pe_w1[64 + t2 + 1] + v2 * pe_w1[128 + t2 + 1] + pe_b1[t2 + 1];
        HHp[tid] = pack2(relu(h0), relu(h1));
    }
    __syncthreads();
    const int c = tid & 127, rh = tid >> 7;
    {
        // src = F@in_w + H@pe_w2 + (in_b + pe_b2); tile uint4 weights
        const unsigned* inH = wH + OFF_IN + c * 4;   // + kp4*512
        const unsigned* peH = wH + OFF_PE + c * 4;
        float acc[4];
        const float base = in_b[c] + pe_b2[c];
#pragma unroll
        for (int r = 0; r < 4; ++r) acc[r] = base;
        for (int kp4 = 0; kp4 < 8; ++kp4) {
            uint4 wi = *(const uint4*)(inH + kp4 * 512);
            uint4 wp = *(const uint4*)(peH + kp4 * 512);
#pragma unroll
            for (int r = 0; r < 4; ++r) {
                const int rr = rh * 4 + r;
                uint4 f = *(const uint4*)(&FHp[rr * 32 + kp4 * 4]);
                uint4 h = *(const uint4*)(&HHp[rr * 32 + kp4 * 4]);
                acc[r] = dot2(f.x, wi.x, acc[r]); acc[r] = dot2(f.y, wi.y, acc[r]);
                acc[r] = dot2(f.z, wi.z, acc[r]); acc[r] = dot2(f.w, wi.w, acc[r]);
                acc[r] = dot2(h.x, wp.x, acc[r]); acc[r] = dot2(h.y, wp.y, acc[r]);
                acc[r] = dot2(h.z, wp.z, acc[r]); acc[r] = dot2(h.w, wp.w, acc[r]);
            }
        }
#pragma unroll
        for (int r = 0; r < 4; ++r) {
            src[(r0 + rh * 4 + r) * 128 + c] = acc[r];
            S[(rh * 4 + r) * 128 + c] = acc[r];
        }
    }
    __syncthreads();
    // pack S -> SH (pairs along the col axis, which is K for q/k/v)
    for (int i = tid; i < 512; i += 256) {
        float2 s = *(const float2*)(&S[i * 2]);
        SH[i] = pack2(s.x, s.y);
    }
    __syncthreads();
    // q/k/v in one pass: 3 coalesced uint4 tile streams, dot2; packed store
    {
        const unsigned* qH = wH + OFF_Q + c * 4;   // + kp4*512
        const unsigned* kH = wH + OFF_K + c * 4;
        const unsigned* vH = wH + OFF_V + c * 4;
        float aq[4], ak[4], av[4];
#pragma unroll
        for (int r = 0; r < 4; ++r) { aq[r] = 0.f; ak[r] = 0.f; av[r] = 0.f; }
        for (int kp4 = 0; kp4 < 16; ++kp4) {
            uint4 wq = *(const uint4*)(qH + kp4 * 512);
            uint4 wk = *(const uint4*)(kH + kp4 * 512);
            uint4 wv = *(const uint4*)(vH + kp4 * 512);
#pragma unroll
            for (int r = 0; r < 4; ++r) {
                uint4 s4 = *(const uint4*)(&SH[(rh * 4 + r) * 64 + kp4 * 4]);
                aq[r] = dot2(s4.x, wq.x, aq[r]); aq[r] = dot2(s4.y, wq.y, aq[r]);
                aq[r] = dot2(s4.z, wq.z, aq[r]); aq[r] = dot2(s4.w, wq.w, aq[r]);
                ak[r] = dot2(s4.x, wk.x, ak[r]); ak[r] = dot2(s4.y, wk.y, ak[r]);
                ak[r] = dot2(s4.z, wk.z, ak[r]); ak[r] = dot2(s4.w, wk.w, ak[r]);
                av[r] = dot2(s4.x, wv.x, av[r]); av[r] = dot2(s4.y, wv.y, av[r]);
                av[r] = dot2(s4.z, wv.z, av[r]); av[r] = dot2(s4.w, wv.w, av[r]);
            }
        }
#pragma unroll
        for (int r = 0; r < 4; ++r) {
            float oq = __shfl_xor(aq[r], 1);
            float ok = __shfl_xor(ak[r], 1);
            float ov = __shfl_xor(av[r], 1);
            if ((c & 1) == 0) {
                const int base = (r0 + rh * 4 + r) * 64 + (c >> 1);
                qs[base] = pack2(aq[r], oq);
                ks[base] = pack2(ak[r], ok);
                vs[base] = pack2(av[r], ov);
            }
        }
    }
}

// ---------------------------------------------------------------------------
// K4: attention + o-proj + LN1 + FFN + LN2 + fusion + BN partials.
// Attention gathers are BRANCH-FREE (clamped index + arithmetic zeroing):
// invalid slots read row 0 (L2-broadcast) and contribute 0 — lets the
// scheduler batch-issue all 16 P@V loads instead of serializing on 18
// divergent branches per thread.
// ---------------------------------------------------------------------------
DEVFN void ln_rows8_pack(float* Cb, unsigned* CHp, const float* __restrict__ g,
                         const float* __restrict__ b, int tid)
{
    const int r = tid >> 5, l = tid & 31;
    float x[4]; float s = 0.f, s2 = 0.f;
#pragma unroll
    for (int i = 0; i < 4; ++i) {
        x[i] = Cb[r * 128 + l * 4 + i];
        s += x[i]; s2 += x[i] * x[i];
    }
#pragma unroll
    for (int o = 1; o < 32; o <<= 1) { s += __shfl_xor(s, o); s2 += __shfl_xor(s2, o); }
    float mu = s * (1.f / 128.f);
    float var = s2 * (1.f / 128.f) - mu * mu;
    float rstd = rsqrtf(var + 1e-5f);
    float y[4];
#pragma unroll
    for (int i = 0; i < 4; ++i) {
        int cc = l * 4 + i;
        y[i] = (x[i] - mu) * rstd * g[cc] + b[cc];
        Cb[r * 128 + cc] = y[i];
    }
    CHp[r * 64 + l * 2]     = pack2(y[0], y[1]);
    CHp[r * 64 + l * 2 + 1] = pack2(y[2], y[3]);
}

__global__ __launch_bounds__(256, 4) void k4_main_cst(
    const float* __restrict__ features, const float* __restrict__ src,
    const unsigned* __restrict__ qs, const unsigned* __restrict__ ks,
    const unsigned* __restrict__ vs,
    const int* __restrict__ nbr,
    const float* __restrict__ q_b, const float* __restrict__ k_b,
    const float* __restrict__ v_b,
    const unsigned* __restrict__ wH,
    const float* __restrict__ o_b,
    const float* __restrict__ n1_g, const float* __restrict__ n1_b,
    const float* __restrict__ l1_b,
    const float* __restrict__ l2_b,
    const float* __restrict__ n3_g, const float* __restrict__ n3_b,
    const float* __restrict__ fu_b,
    float* __restrict__ fused, float* __restrict__ bnSum, float* __restrict__ bnSq)
{
    __shared__ __align__(16) float A[1024];        // src tile; P5 BN staging
    __shared__ __align__(16) float C[1024];        // running activation f32
    __shared__ __align__(16) float Q[1024];        // q rows f32 (bias applied)
    __shared__ __align__(16) unsigned QH[512];     // q rows packed 8x64
    __shared__ __align__(16) float SC[512];        // attention scores
    __shared__ __align__(16) unsigned BtH[512];    // head_out packed 8x64
    __shared__ __align__(16) unsigned CH[512];     // tgt packed 8x64
    __shared__ __align__(16) unsigned FH[256];     // features packed 8x32
    __shared__ __align__(16) _Float16 Hh[2048];    // ffn hidden f16 8x256
    __shared__ __align__(16) float bK[128], bV[128];
    __shared__ int idxL[128];
    const int tid = threadIdx.x;
    const int r0 = blockIdx.x * 8;

    for (int i = tid; i < 1024; i += 256) A[i] = src[r0 * 128 + i];
    if (tid < 256) {
        float2 f = *(const float2*)(features + r0 * 64 + tid * 2);
        FH[tid] = pack2(f.x, f.y);
    }
    if (tid < 128) {
        idxL[tid] = nbr[r0 * 16 + tid];
        bK[tid] = k_b[tid]; bV[tid] = v_b[tid];
    }
    __syncthreads();
    if (tid < 128) {   // Q gather + bias: thread = (row=tid>>4, cg=tid&15)
        int r = tid >> 4, cg = tid & 15;
        int i0 = idxL[r * 16];
        uint4 qv = make_uint4(0u, 0u, 0u, 0u);
        if (i0 >= 0) qv = *(const uint4*)(qs + i0 * 64 + cg * 4);
        float2 u0 = unpk(qv.x), u1 = unpk(qv.y), u2 = unpk(qv.z), u3 = unpk(qv.w);
        float4 b0 = *(const float4*)(q_b + cg * 8);
        float4 b1 = *(const float4*)(q_b + cg * 8 + 4);
        float q0 = u0.x + b0.x, q1 = u0.y + b0.y, q2 = u1.x + b0.z, q3 = u1.y + b0.w;
        float q4 = u2.x + b1.x, q5 = u2.y + b1.y, q6 = u3.x + b1.z, q7 = u3.y + b1.w;
        *(float4*)(&Q[r * 128 + cg * 8])     = make_float4(q0, q1, q2, q3);
        *(float4*)(&Q[r * 128 + cg * 8 + 4]) = make_float4(q4, q5, q6, q7);
        QH[r * 64 + cg * 4 + 0] = pack2(q0, q1);
        QH[r * 64 + cg * 4 + 1] = pack2(q2, q3);
        QH[r * 64 + cg * 4 + 2] = pack2(q4, q5);
        QH[r * 64 + cg * 4 + 3] = pack2(q6, q7);
    }
    __syncthreads();

    // ---- phase 1a: scores. thread = (row r, head h, group g of 8) --------
    // Branch-free: clamped index, s zeroed arithmetically for invalid.
    const int ar = tid >> 5, ah = (tid >> 3) & 3, ag = tid & 7;
    {
        const int ch = ag & 3;
        float sbias = 0.f;
#pragma unroll
        for (int c4 = 0; c4 < 8; ++c4) {
            float4 qv = *(const float4*)(&Q[ar * 128 + ah * 32 + c4 * 4]);
            float4 kb = *(const float4*)(&bK[ch * 32 + c4 * 4]);
            sbias += qv.x * kb.x + qv.y * kb.y + qv.z * kb.z + qv.w * kb.w;
        }
#pragma unroll
        for (int jj = 0; jj < 2; ++jj) {
            int j = ag + jj * 8;
            int j4 = j >> 2;
            int id = idxL[ar * 16 + ah * 4 + j4];
            int idc = id >= 0 ? id : 0;
            const unsigned* kr = ks + idc * 64 + ch * 16;
            float s = 0.f;
#pragma unroll
            for (int c4 = 0; c4 < 4; ++c4) {
                uint4 kv = *(const uint4*)(kr + c4 * 4);
                uint4 qv = *(const uint4*)(&QH[ar * 64 + ah * 16 + c4 * 4]);
                s = dot2(qv.x, kv.x, s); s = dot2(qv.y, kv.y, s);
                s = dot2(qv.z, kv.z, s); s = dot2(qv.w, kv.w, s);
            }
            s = id >= 0 ? s : 0.f;
            SC[ar * 64 + ah * 16 + j] = (s + sbias) * 0.08838834764831845f;
        }
    }
    __syncthreads();

    // ---- phase 1b: softmax + P@V (branch-free gathers) -------------------
    {
        float p[16];
        float mx = -3.4e38f;
#pragma unroll
        for (int j = 0; j < 16; ++j) { p[j] = SC[ar * 64 + ah * 16 + j]; mx = fmaxf(mx, p[j]); }
        float sum = 0.f;
#pragma unroll
        for (int j = 0; j < 16; ++j) { p[j] = __expf(p[j] - mx); sum += p[j]; }
        float inv = 1.f / sum;
        float4 acc = make_float4(0.f, 0.f, 0.f, 0.f);
#pragma unroll
        for (int j = 0; j < 16; ++j) {
            int j4 = j >> 2, ch = j & 3;
            int id = idxL[ar * 16 + ah * 4 + j4];
            int idc = id >= 0 ? id : 0;
            float wm = id >= 0 ? p[j] * inv : 0.f;
            uint2 vv = *(const uint2*)(vs + idc * 64 + ch * 16 + ag * 2);
            float2 v01 = unpk(vv.x), v23 = unpk(vv.y);
            acc.x += wm * v01.x; acc.y += wm * v01.y;
            acc.z += wm * v23.x; acc.w += wm * v23.y;
        }
        float4 vb = *(const float4*)(&bV[ah * 32 + ag * 4]);
        acc.x += vb.x; acc.y += vb.y; acc.z += vb.z; acc.w += vb.w;
        BtH[ar * 64 + ah * 16 + ag * 2]     = pack2(acc.x, acc.y);
        BtH[ar * 64 + ah * 16 + ag * 2 + 1] = pack2(acc.z, acc.w);
    }
    __syncthreads();

    // ---- phase 2: C = A + head_out @ o_w + o_b (tile uint4 w) ------------
    {
        const int c = tid & 127, rh = tid >> 7;
        const unsigned* oH = wH + OFF_O + c * 4;   // + kp4*512
        float acc[4];
#pragma unroll
        for (int r = 0; r < 4; ++r) acc[r] = 0.f;
        for (int kp4 = 0; kp4 < 16; ++kp4) {
            uint4 w = *(const uint4*)(oH + kp4 * 512);
#pragma unroll
            for (int r = 0; r < 4; ++r) {
                uint4 t = *(const uint4*)(&BtH[(rh * 4 + r) * 64 + kp4 * 4]);
                acc[r] = dot2(t.x, w.x, acc[r]); acc[r] = dot2(t.y, w.y, acc[r]);
                acc[r] = dot2(t.z, w.z, acc[r]); acc[r] = dot2(t.w, w.w, acc[r]);
            }
        }
        const float ob = o_b[c];
#pragma unroll
        for (int r = 0; r < 4; ++r) {
            const int rr = rh * 4 + r;
            C[rr * 128 + c] = A[rr * 128 + c] + ob + acc[r];
        }
    }
    __syncthreads();
    ln_rows8_pack(C, CH, n1_g, n1_b, tid);   // C = tgt (f32 + packed)
    __syncthreads();

    // ---- phase 3: Hh = relu(CH @ l1_w + l1_b)  [8 x 256] f16 out ---------
    {
        const int f = tid;
        const unsigned* l1H = wH + OFF_L1 + f * 4;   // + kp4*1024 (C=256)
        float acc[8];
#pragma unroll
        for (int r = 0; r < 8; ++r) acc[r] = 0.f;
        for (int kp4 = 0; kp4 < 16; ++kp4) {
            uint4 w = *(const uint4*)(l1H + kp4 * 1024);
#pragma unroll
            for (int r = 0; r < 8; ++r) {
                uint4 t = *(const uint4*)(&CH[r * 64 + kp4 * 4]);
                acc[r] = dot2(t.x, w.x, acc[r]); acc[r] = dot2(t.y, w.y, acc[r]);
                acc[r] = dot2(t.z, w.z, acc[r]); acc[r] = dot2(t.w, w.w, acc[r]);
            }
        }
        const float bb = l1_b[f];
#pragma unroll
        for (int r = 0; r < 8; ++r) Hh[r * 256 + f] = (_Float16)relu(acc[r] + bb);
    }
    __syncthreads();

    // ---- phase 4: C += Hh @ l2_w + l2_b (K=256, tile uint4 w) ------------
    {
        const int c = tid & 127, rh = tid >> 7;
        const unsigned* l2H = wH + OFF_L2 + c * 4;   // + kp4*512, kp4 0..31
        const unsigned* HhU = (const unsigned*)Hh;   // 8 x 128 dwords
        float acc[4];
#pragma unroll
        for (int r = 0; r < 4; ++r) acc[r] = 0.f;
        for (int kp4 = 0; kp4 < 32; ++kp4) {
            uint4 w = *(const uint4*)(l2H + kp4 * 512);
#pragma unroll
            for (int r = 0; r < 4; ++r) {
                uint4 t = *(const uint4*)(&HhU[(rh * 4 + r) * 128 + kp4 * 4]);
                acc[r] = dot2(t.x, w.x, acc[r]); acc[r] = dot2(t.y, w.y, acc[r]);
                acc[r] = dot2(t.z, w.z, acc[r]); acc[r] = dot2(t.w, w.w, acc[r]);
            }
        }
        const float lb = l2_b[c];
#pragma unroll
        for (int r = 0; r < 4; ++r) {
            const int rr = rh * 4 + r;
            C[rr * 128 + c] += lb + acc[r];
        }
    }
    __syncthreads();
    ln_rows8_pack(C, CH, n3_g, n3_b, tid);   // C = final tgt (f32 + packed)
    __syncthreads();

    // ---- phase 5: fused = [F, C] @ fu_w + fu_b; BN staging in A ----------
    {
        const int c = tid & 63, rg = tid >> 6;   // 4 groups x 2 rows
        const unsigned* fuH = wH + OFF_FU + c * 4;   // + kp4*256 (C=64)
        float acc[2];
        const float fb = fu_b[c];
#pragma unroll
        for (int r = 0; r < 2; ++r) acc[r] = fb;
        for (int kp4 = 0; kp4 < 8; ++kp4) {      // features half: kp4 0..7
            uint4 w = *(const uint4*)(fuH + kp4 * 256);
#pragma unroll
            for (int r = 0; r < 2; ++r) {
                uint4 t = *(const uint4*)(&FH[(rg * 2 + r) * 32 + kp4 * 4]);
                acc[r] = dot2(t.x, w.x, acc[r]); acc[r] = dot2(t.y, w.y, acc[r]);
                acc[r] = dot2(t.z, w.z, acc[r]); acc[r] = dot2(t.w, w.w, acc[r]);
            }
        }
        for (int kp4 = 0; kp4 < 16; ++kp4) {     // tgt half: kp4 8..23
            uint4 w = *(const uint4*)(fuH + (8 + kp4) * 256);
#pragma unroll
            for (int r = 0; r < 2; ++r) {
                uint4 t = *(const uint4*)(&CH[(rg * 2 + r) * 64 + kp4 * 4]);
                acc[r] = dot2(t.x, w.x, acc[r]); acc[r] = dot2(t.y, w.y, acc[r]);
                acc[r] = dot2(t.z, w.z, acc[r]); acc[r] = dot2(t.w, w.w, acc[r]);
            }
        }
#pragma unroll
        for (int r = 0; r < 2; ++r) {
            int row = rg * 2 + r;
            float v = acc[r];
            fused[(r0 + row) * 64 + c] = v;
            A[row * 64 + c] = v;
        }
    }
    __syncthreads();
    if (tid < 64) {
        float s = 0.f, s2 = 0.f;
#pragma unroll
        for (int r = 0; r < 8; ++r) { float x = A[r * 64 + tid]; s += x; s2 += x * x; }
        atomicAdd(&bnSum[tid], s);
        atomicAdd(&bnSq[tid], s2);
    }
}

// ---------------------------------------------------------------------------
// K5: batchnorm (train-mode stats) + relu -> fp32 out
// ---------------------------------------------------------------------------
__global__ __launch_bounds__(256) void k5_bn_cst(
    const float* __restrict__ fused, const float* __restrict__ bnSum,
    const float* __restrict__ bnSq,
    const float* __restrict__ g, const float* __restrict__ b,
    float* __restrict__ out, int N)
{
    const int total = N * 64;
    const float invN = 1.f / (float)N;
    for (int i = blockIdx.x * 256 + threadIdx.x; i < total; i += gridDim.x * 256) {
        int c = i & 63;
        float mu = bnSum[c] * invN;
        float var = bnSq[c] * invN - mu * mu;
        float x = fused[i];
        float y = (x - mu) * rsqrtf(var + 1e-3f) * g[c] + b[c];
        out[i] = relu(y);
    }
}

// ---------------------------------------------------------------------------
extern "C" void kernel_launch(void* const* d_in, const int* in_sizes, int n_in,
                              void* d_out, int out_size, void* d_ws, size_t ws_size,
                              hipStream_t stream)
{
    const float* features = (const float*)d_in[0];
    const int*   coords   = (const int*)d_in[1];
    const float* pe_w1 = (const float*)d_in[2];
    const float* pe_b1 = (const float*)d_in[3];
    const float* pe_w2 = (const float*)d_in[4];
    const float* pe_b2 = (const float*)d_in[5];
    const float* in_w  = (const float*)d_in[6];
    const float* in_b  = (const float*)d_in[7];
    const float* q_w   = (const float*)d_in[8];
    const float* q_b   = (const float*)d_in[9];
    const float* k_w   = (const float*)d_in[10];
    const float* k_b   = (const float*)d_in[11];
    const float* v_w   = (const float*)d_in[12];
    const float* v_b   = (const float*)d_in[13];
    const float* o_w   = (const float*)d_in[14];
    const float* o_b   = (const float*)d_in[15];
    const float* n1_g  = (const float*)d_in[16];
    const float* n1_b  = (const float*)d_in[17];
    const float* l1_w  = (const float*)d_in[18];
    const float* l1_b  = (const float*)d_in[19];
    const float* l2_w  = (const float*)d_in[20];
    const float* l2_b  = (const float*)d_in[21];
    const float* n3_g  = (const float*)d_in[22];
    const float* n3_b  = (const float*)d_in[23];
    const float* fu_w  = (const float*)d_in[24];
    const float* fu_b  = (const float*)d_in[25];
    const float* bn_g  = (const float*)d_in[26];
    const float* bn_b  = (const float*)d_in[27];

    const int N = in_sizes[0] / 64;   // 8192

    float*    src   = (float*)d_ws;                    // N*128 f32
    unsigned* qs    = (unsigned*)(src + (size_t)N * 128);  // N*64 packed
    unsigned* ks    = qs + (size_t)N * 64;             // N*64 packed
    unsigned* vs    = ks + (size_t)N * 64;             // N*64 packed
    float*    fused = (float*)(vs + (size_t)N * 64);   // N*64 f32
    int*      nbr   = (int*)(fused + (size_t)N * 64);  // N*16 ints
    float*    bnSum = (float*)(nbr + (size_t)N * 16);  // 64
    float*    bnSq  = bnSum + 64;                      // 64 (contiguous 128)
    unsigned* wH    = (unsigned*)(bnSq + 64);          // packed weights (~320 KB)
    unsigned* pcoords = wH + PACKED_TOTAL;             // N packed byte-coords

    k0_pack<<<64, 256, 0, stream>>>(q_w, k_w, v_w, o_w, l1_w, l2_w,
                                    in_w, pe_w2, fu_w, coords, wH, pcoords, N);
    ka_pre_cst<<<N / 8 + N / 16, 256, 0, stream>>>(features, coords, pcoords,
                                                   pe_w1, pe_b1, pe_b2, in_b,
                                                   wH,
                                                   src, qs, ks, vs, nbr, bnSum, N);
    k4_main_cst<<<N / 8, 256, 0, stream>>>(features, src, qs, ks, vs, nbr,
                                           q_b, k_b, v_b, wH, o_b, n1_g, n1_b,
                                           l1_b, l2_b, n3_g, n3_b,
                                           fu_b, fused, bnSum, bnSq);
    k5_bn_cst<<<512, 256, 0, stream>>>(fused, bnSum, bnSq, bn_g, bn_b,
                                       (float*)d_out, N);
}